// Round 3
// baseline (3969.103 us; speedup 1.0000x reference)
//
#include <hip/hip_runtime.h>
#include <hip/hip_bf16.h>
#include <math.h>

// ---- problem constants ----
constexpr int Dd  = 768;    // D
constexpr int NH  = 12;     // heads
constexpr int DHd = 64;     // head dim
constexpr int Bn  = 8;      // batch
constexpr int TVn = 512;    // video tokens
constexpr int TSn = 128;    // script tokens
constexpr int NST = 8;      // steps
constexpr int An  = 16;     // answers
constexpr int DPn = 3072;   // D*(3+M)
constexpr int GSn = 2304;   // 3*768

// dtype policy (evidence: R1 bf16-read -> NaN (f32 mantissa halves), R2 bf16
// out-write -> upper half of f32 out buffer left zero, err == max|ref|):
// inputs f32, output f32.
using inT  = float;
using outT = float;

__device__ inline float toF(float x) { return x; }
__device__ inline float toF(__hip_bfloat16 x) { return __bfloat162float(x); }

// ---------------------------------------------------------------------------
// NT GEMM: C[m*ldc+n] = A[m*lda+k] dot Bw[n*K+k] + bias[n], optional ReLU.
// 64x64 tile, BK=16, 256 threads, 4x4 acc per thread.
// ---------------------------------------------------------------------------
template <typename TA>
__global__ __launch_bounds__(256) void gemm_nt(const TA* __restrict__ A,
                                               const inT* __restrict__ Bw,
                                               const inT* __restrict__ bias,
                                               float* __restrict__ C,
                                               int M, int N, int K,
                                               int lda, int ldc, int relu) {
  __shared__ float As[16][65];
  __shared__ float Bs[16][65];
  int bm = blockIdx.y * 64, bn = blockIdx.x * 64;
  int tid = threadIdx.x;
  int tx = tid & 15, ty = tid >> 4;
  float acc[4][4] = {};
  for (int k0 = 0; k0 < K; k0 += 16) {
#pragma unroll
    for (int i = 0; i < 4; i++) {
      int l = tid * 4 + i;
      int row = l >> 4, kk = l & 15;
      float v = 0.f;
      if (bm + row < M) v = toF(A[(size_t)(bm + row) * lda + k0 + kk]);
      As[kk][row] = v;
    }
#pragma unroll
    for (int i = 0; i < 4; i++) {
      int l = tid * 4 + i;
      int row = l >> 4, kk = l & 15;
      float v = 0.f;
      if (bn + row < N) v = toF(Bw[(size_t)(bn + row) * K + k0 + kk]);
      Bs[kk][row] = v;
    }
    __syncthreads();
#pragma unroll
    for (int kk = 0; kk < 16; kk++) {
      float a4[4], b4[4];
#pragma unroll
      for (int i = 0; i < 4; i++) a4[i] = As[kk][ty * 4 + i];
#pragma unroll
      for (int j = 0; j < 4; j++) b4[j] = Bs[kk][tx * 4 + j];
#pragma unroll
      for (int i = 0; i < 4; i++)
#pragma unroll
        for (int j = 0; j < 4; j++) acc[i][j] += a4[i] * b4[j];
    }
    __syncthreads();
  }
#pragma unroll
  for (int i = 0; i < 4; i++) {
    int m = bm + ty * 4 + i;
    if (m >= M) continue;
#pragma unroll
    for (int j = 0; j < 4; j++) {
      int n = bn + tx * 4 + j;
      if (n >= N) continue;
      float v = acc[i][j] + toF(bias[n]);
      if (relu) v = fmaxf(v, 0.f);
      C[(size_t)m * ldc + n] = v;
    }
  }
}

// ---------------------------------------------------------------------------
// QK^T: group g = outer*NH + h. qrow0=(g/NH)*Tq, krow0=(g/(NH*kdiv))*Tk.
// ---------------------------------------------------------------------------
__global__ __launch_bounds__(256) void att_qk(const float* __restrict__ qp,
                                              const float* __restrict__ kp,
                                              float* __restrict__ Sout,
                                              int Tq, int Tk, int kdiv, float scale) {
  int g = blockIdx.x;
  int h = g % NH;
  int qrow0 = (g / NH) * Tq;
  int krow0 = (g / (NH * kdiv)) * Tk;
  int q0 = blockIdx.y * 32;
  int k0 = blockIdx.z * 64;
  __shared__ float Qs[32][DHd + 1];
  __shared__ float Ks[64][DHd + 1];
  int tid = threadIdx.x;
  {
    int row = tid >> 3, db = (tid & 7) * 8;
    int qr = q0 + row;
#pragma unroll
    for (int i = 0; i < 8; i++) {
      float v = 0.f;
      if (qr < Tq) v = qp[(size_t)(qrow0 + qr) * Dd + h * DHd + db + i];
      Qs[row][db + i] = v;
    }
  }
#pragma unroll
  for (int half = 0; half < 2; half++) {
    int row = (tid >> 3) + half * 32, db = (tid & 7) * 8;
    int kr = k0 + row;
#pragma unroll
    for (int i = 0; i < 8; i++) {
      float v = 0.f;
      if (kr < Tk) v = kp[(size_t)(krow0 + kr) * Dd + h * DHd + db + i];
      Ks[row][db + i] = v;
    }
  }
  __syncthreads();
  int q = tid >> 3, kg = tid & 7;
  float acc[8] = {};
  for (int d = 0; d < DHd; d++) {
    float qv = Qs[q][d];
#pragma unroll
    for (int j = 0; j < 8; j++) acc[j] += qv * Ks[kg * 8 + j][d];
  }
  if (q0 + q < Tq) {
    size_t base = ((size_t)g * Tq + q0 + q) * Tk + k0 + kg * 8;
#pragma unroll
    for (int j = 0; j < 8; j++) Sout[base + j] = acc[j] * scale;
  }
}

// ---------------------------------------------------------------------------
// P@V: Out[qrow0+q, h*64+d] = sum_k P[g,q,k] * vp[krow0+k, h*64+d]
// ---------------------------------------------------------------------------
__global__ __launch_bounds__(256) void att_pv(const float* __restrict__ P,
                                              const float* __restrict__ vp,
                                              float* __restrict__ Out,
                                              int Tq, int Tk, int kdiv) {
  int g = blockIdx.x;
  int h = g % NH;
  int qrow0 = (g / NH) * Tq;
  int krow0 = (g / (NH * kdiv)) * Tk;
  int q0 = blockIdx.y * 32;
  __shared__ float Ps[32][65];
  __shared__ float Vs[64][DHd + 1];
  int tid = threadIdx.x;
  int q = tid >> 3, dg = tid & 7;
  float acc[8] = {};
  for (int k0 = 0; k0 < Tk; k0 += 64) {
    {
      int row = tid >> 3, cb = (tid & 7) * 8;
      int qr = q0 + row;
#pragma unroll
      for (int i = 0; i < 8; i++) {
        float v = 0.f;
        if (qr < Tq) v = P[((size_t)g * Tq + qr) * Tk + k0 + cb + i];
        Ps[row][cb + i] = v;
      }
    }
#pragma unroll
    for (int half = 0; half < 2; half++) {
      int row = (tid >> 3) + half * 32, db = (tid & 7) * 8;
#pragma unroll
      for (int i = 0; i < 8; i++)
        Vs[row][db + i] = vp[(size_t)(krow0 + k0 + row) * Dd + h * DHd + db + i];
    }
    __syncthreads();
    for (int kk = 0; kk < 64; kk++) {
      float p = Ps[q][kk];
#pragma unroll
      for (int j = 0; j < 8; j++) acc[j] += p * Vs[kk][dg * 8 + j];
    }
    __syncthreads();
  }
  if (q0 + q < Tq) {
    size_t base = (size_t)(qrow0 + q0 + q) * Dd + h * DHd + dg * 8;
#pragma unroll
    for (int j = 0; j < 8; j++) Out[base + j] = acc[j];
  }
}

// row-wise softmax in place; one 256-thread block per row
__global__ __launch_bounds__(256) void softmax_rows(float* __restrict__ X, int len) {
  int row = blockIdx.x;
  float* p = X + (size_t)row * len;
  int tid = threadIdx.x;
  __shared__ float red[4];
  __shared__ float red2[4];
  float lmax = -1e30f;
  for (int j = tid; j < len; j += 256) lmax = fmaxf(lmax, p[j]);
  for (int off = 32; off; off >>= 1) lmax = fmaxf(lmax, __shfl_down(lmax, off));
  if ((tid & 63) == 0) red[tid >> 6] = lmax;
  __syncthreads();
  if (tid == 0) red[0] = fmaxf(fmaxf(red[0], red[1]), fmaxf(red[2], red[3]));
  __syncthreads();
  float m = red[0];
  float lsum = 0.f;
  for (int j = tid; j < len; j += 256) {
    float e = expf(p[j] - m);
    p[j] = e;
    lsum += e;
  }
  for (int off = 32; off; off >>= 1) lsum += __shfl_down(lsum, off);
  if ((tid & 63) == 0) red2[tid >> 6] = lsum;
  __syncthreads();
  if (tid == 0) red2[0] = red2[0] + red2[1] + red2[2] + red2[3];
  __syncthreads();
  float inv = 1.f / red2[0];
  for (int j = tid; j < len; j += 256) p[j] *= inv;
}

// W[(b,s,a),k] = mean_h softmax'd S2
__global__ void wmean_k(const float* __restrict__ S2, float* __restrict__ W) {
  int idx = blockIdx.x * 256 + threadIdx.x;
  if (idx >= Bn * NST * An * TSn) return;
  int k = idx % TSn;
  int rest = idx / TSn;
  int a = rest % An;
  int bs = rest / An;
  float acc = 0.f;
  for (int h = 0; h < NH; h++)
    acc += S2[(((size_t)bs * NH + h) * An + a) * TSn + k];
  W[idx] = acc * (1.f / NH);
}

// cat[row*DPn + 2*Dd + j] = qf[b,j] + at[row,j]
__global__ void qa_add(const float* __restrict__ qf, const float* __restrict__ at,
                       float* __restrict__ cat) {
  int idx = blockIdx.x * 256 + threadIdx.x;
  if (idx >= Bn * NST * An * Dd) return;
  int b = idx / (NST * An * Dd);
  int row = idx / Dd;
  int j = idx % Dd;
  cat[(size_t)row * DPn + 2 * Dd + j] = qf[b * Dd + j] + at[idx];
}

// cat[row*DPn + j] = sum_k W[row,k] * vatt[b*TS+k, j]
__global__ __launch_bounds__(256) void qv_k(const float* __restrict__ W,
                                            const float* __restrict__ vatt,
                                            float* __restrict__ cat) {
  int row = blockIdx.x;
  int j = blockIdx.y * 256 + threadIdx.x;
  if (j >= Dd) return;
  int b = row / (NST * An);
  float acc = 0.f;
  for (int k = 0; k < TSn; k++)
    acc += W[(size_t)row * TSn + k] * vatt[((size_t)b * TSn + k) * Dd + j];
  cat[(size_t)row * DPn + j] = acc;
}

__global__ void state_init(const inT* __restrict__ s0, float* __restrict__ state) {
  int idx = blockIdx.x * 256 + threadIdx.x;
  if (idx >= Bn * Dd) return;
  state[idx] = toF(s0[idx % Dd]);
}

// GRU elementwise combine for step s
__global__ void gru_combine(const float* __restrict__ gi, const float* __restrict__ gh,
                            const float* __restrict__ state, float* __restrict__ hout, int s) {
  int idx = blockIdx.x * 256 + threadIdx.x;
  if (idx >= Bn * An * Dd) return;
  int j = idx % Dd;
  int r = idx / Dd;
  int b = r / An, a = r % An;
  size_t girow = ((size_t)(b * NST + s) * An + a);
  const float* gip = gi + girow * GSn;
  const float* ghp = gh + (size_t)b * GSn;
  float ir = gip[j], iz = gip[Dd + j], inn = gip[2 * Dd + j];
  float hr = ghp[j], hz = ghp[Dd + j], hn = ghp[2 * Dd + j];
  float rg = 1.f / (1.f + expf(-(ir + hr)));
  float zg = 1.f / (1.f + expf(-(iz + hz)));
  float ng = tanhf(inn + rg * hn);
  float st = state[b * Dd + j];
  hout[idx] = (1.f - zg) * ng + zg * st;
}

// logits -> argmax -> state update -> output write; one block per b
__global__ __launch_bounds__(256) void tail_k(const float* __restrict__ ph,
                                              const inT* __restrict__ pw2,
                                              const inT* __restrict__ pb2,
                                              const float* __restrict__ inp_s,
                                              float* __restrict__ state,
                                              outT* __restrict__ out, int s) {
  int b = blockIdx.x;
  int tid = threadIdx.x;
  int wave = tid >> 6, lane = tid & 63;
  __shared__ float slog[An];
  __shared__ int samax;
  for (int a = wave; a < An; a += 4) {
    const float* row = ph + (size_t)(b * An + a) * Dd;
    float acc = 0.f;
    for (int j = lane; j < Dd; j += 64) acc += row[j] * toF(pw2[j]);
    for (int off = 32; off; off >>= 1) acc += __shfl_down(acc, off);
    if (lane == 0) slog[a] = acc + toF(pb2[0]);
  }
  __syncthreads();
  if (tid == 0) {
    float best = slog[0];
    int bi = 0;
    for (int a = 1; a < An; a++)
      if (slog[a] > best) { best = slog[a]; bi = a; }
    samax = bi;
  }
  __syncthreads();
  if (tid < An) out[(size_t)(b * NST + s) * An + tid] = slog[tid];
  int am = samax;
  size_t srow = ((size_t)(b * NST + s) * An + am) * (size_t)Dd;
  for (int j = tid; j < Dd; j += 256) state[b * Dd + j] = inp_s[srow + j];
}

// ---------------------------------------------------------------------------
static inline void gemm_f(const float* A, const inT* W, const inT* bias, float* C,
                          int M, int N, int K, int lda, int ldc, int relu, hipStream_t st) {
  dim3 g((N + 63) / 64, (M + 63) / 64);
  gemm_nt<float><<<g, 256, 0, st>>>(A, W, bias, C, M, N, K, lda, ldc, relu);
}
static inline void gemm_i(const inT* A, const inT* W, const inT* bias, float* C,
                          int M, int N, int K, int lda, int ldc, int relu, hipStream_t st) {
  dim3 g((N + 63) / 64, (M + 63) / 64);
  gemm_nt<inT><<<g, 256, 0, st>>>(A, W, bias, C, M, N, K, lda, ldc, relu);
}

extern "C" void kernel_launch(void* const* d_in, const int* in_sizes, int n_in,
                              void* d_out, int out_size, void* d_ws, size_t ws_size,
                              hipStream_t stream) {
  const inT* video     = (const inT*)d_in[0];
  const inT* script    = (const inT*)d_in[1];
  const inT* question  = (const inT*)d_in[2];
  const inT* a_texts   = (const inT*)d_in[3];
  const inT* a_buttons = (const inT*)d_in[4];
  const inT* v_w1 = (const inT*)d_in[5];
  const inT* v_b1 = (const inT*)d_in[6];
  const inT* v_w2 = (const inT*)d_in[7];
  const inT* v_b2 = (const inT*)d_in[8];
  const inT* t_w1 = (const inT*)d_in[9];
  const inT* t_b1 = (const inT*)d_in[10];
  const inT* t_w2 = (const inT*)d_in[11];
  const inT* t_b2 = (const inT*)d_in[12];
  const inT* pre_w1 = (const inT*)d_in[13];
  const inT* pre_b1 = (const inT*)d_in[14];
  const inT* pre_w2 = (const inT*)d_in[15];
  const inT* pre_b2 = (const inT*)d_in[16];
  const inT* s2v_win  = (const inT*)d_in[17];
  const inT* s2v_bin  = (const inT*)d_in[18];
  const inT* s2v_wout = (const inT*)d_in[19];
  const inT* s2v_bout = (const inT*)d_in[20];
  const inT* qa_win  = (const inT*)d_in[21];
  const inT* qa_bin  = (const inT*)d_in[22];
  const inT* qa_wout = (const inT*)d_in[23];
  const inT* qa_bout = (const inT*)d_in[24];
  const inT* gru_wih = (const inT*)d_in[25];
  const inT* gru_whh = (const inT*)d_in[26];
  const inT* gru_bih = (const inT*)d_in[27];
  const inT* gru_bhh = (const inT*)d_in[28];
  const inT* proj_w1 = (const inT*)d_in[29];
  const inT* proj_b1 = (const inT*)d_in[30];
  const inT* proj_w2 = (const inT*)d_in[31];
  const inT* proj_b2 = (const inT*)d_in[32];
  const inT* state0  = (const inT*)d_in[33];

  // ---- workspace arena with lifetime overlays (total ~95 MB) ----
  constexpr size_t M1 = (size_t)4096 * Dd;   // 3,145,728 floats
  constexpr size_t SM = (size_t)1024 * Dd;   //   786,432 floats
  float* ws = (float*)d_ws;
  float* v      = ws;                 // M1, phase A..s2v
  float* kregion= ws + M1;            // M1: kproj -> ab-hidden -> preh
  float* vregion= ws + 2 * M1;        // M1: vproj -> gi
  float* X      = ws + 3 * M1;        // 2*M1: htmp -> S1 -> {cat | S2 | wmean}
  float* sc     = ws + 5 * M1;
  float* at     = sc + SM;
  float* qproj  = at + SM;
  float* attnout= qproj + SM;
  float* vatt   = attnout + SM;
  float* kp2    = vatt + SM;
  float* vp2    = kp2 + SM;
  float* qp2    = vp2 + SM;
  float* attnout2 = qp2 + SM;
  float* inp_s  = attnout2 + SM;
  float* qf     = inp_s + SM;                     // 6144
  float* state  = qf + Bn * Dd;                   // 6144
  float* gh     = state + Bn * Dd;                // 18432
  float* hbuf   = gh + (size_t)Bn * GSn;          // 98304
  float* phb    = hbuf + (size_t)Bn * An * Dd;    // 98304
  float* htmp  = X;
  float* S1    = X;            // 6,291,456 = 2*M1 exactly
  float* cat   = X;            // 1024*3072 = M1
  float* S2    = X + M1;       // 1,572,864
  float* wmean = X + M1 + (size_t)Bn * NST * NH * An * TSn;  // 131,072
  (void)ws_size; (void)in_sizes; (void)n_in; (void)out_size;

  // ---- phase A: batched MLPs (htmp lives in X) ----
  gemm_i(video, v_w1, v_b1, htmp, 4096, Dd, Dd, Dd, Dd, 1, stream);
  gemm_f(htmp, v_w2, v_b2, v, 4096, Dd, Dd, Dd, Dd, 0, stream);
  gemm_i(script, t_w1, t_b1, htmp, 1024, Dd, Dd, Dd, Dd, 1, stream);
  gemm_f(htmp, t_w2, t_b2, sc, 1024, Dd, Dd, Dd, Dd, 0, stream);
  gemm_i(question, t_w1, t_b1, htmp, Bn, Dd, Dd, Dd, Dd, 1, stream);
  gemm_f(htmp, t_w2, t_b2, qf, Bn, Dd, Dd, Dd, Dd, 0, stream);
  gemm_i(a_texts, t_w1, t_b1, htmp, 1024, Dd, Dd, Dd, Dd, 1, stream);
  gemm_f(htmp, t_w2, t_b2, at, 1024, Dd, Dd, Dd, Dd, 0, stream);

  // ---- s2v attention: Q=sc, K=V=v (htmp dead; S1 takes X) ----
  gemm_f(v, s2v_win + (size_t)Dd * Dd, s2v_bin + Dd, kregion, 4096, Dd, Dd, Dd, Dd, 0, stream);
  gemm_f(v, s2v_win + 2 * (size_t)Dd * Dd, s2v_bin + 2 * Dd, vregion, 4096, Dd, Dd, Dd, Dd, 0, stream);
  gemm_f(sc, s2v_win, s2v_bin, qproj, 1024, Dd, Dd, Dd, Dd, 0, stream);
  att_qk<<<dim3(Bn * NH, TSn / 32, TVn / 64), 256, 0, stream>>>(qproj, kregion, S1, TSn, TVn, 1, 0.125f);
  softmax_rows<<<Bn * NH * TSn, 256, 0, stream>>>(S1, TVn);
  att_pv<<<dim3(Bn * NH, TSn / 32), 256, 0, stream>>>(S1, vregion, attnout, TSn, TVn, 1);
  gemm_f(attnout, s2v_wout, s2v_bout, vatt, 1024, Dd, Dd, Dd, Dd, 0, stream);

  // ---- phase B (S1 dead; cat/S2 take X; kregion free for ab-hidden) ----
  gemm_i(a_buttons, v_w1, v_b1, kregion, 1024, Dd, Dd, Dd, Dd, 1, stream);
  gemm_f(kregion, v_w2, v_b2, cat + 3 * Dd, 1024, Dd, Dd, Dd, DPn, 0, stream);  // ab2 slice
  qa_add<<<(1024 * Dd + 255) / 256, 256, 0, stream>>>(qf, at, cat);             // qa slice
  gemm_f(sc, qa_win + (size_t)Dd * Dd, qa_bin + Dd, kp2, 1024, Dd, Dd, Dd, Dd, 0, stream);
  gemm_f(sc, qa_win + 2 * (size_t)Dd * Dd, qa_bin + 2 * Dd, vp2, 1024, Dd, Dd, Dd, Dd, 0, stream);
  gemm_f(cat + 2 * Dd, qa_win, qa_bin, qp2, 1024, Dd, Dd, DPn, Dd, 0, stream);
  att_qk<<<dim3(Bn * NST * NH, 1, TSn / 64), 256, 0, stream>>>(qp2, kp2, S2, An, TSn, NST, 0.125f);
  softmax_rows<<<Bn * NST * NH * An, 256, 0, stream>>>(S2, TSn);
  att_pv<<<dim3(Bn * NST * NH, 1), 256, 0, stream>>>(S2, vp2, attnout2, An, TSn, NST);
  gemm_f(attnout2, qa_wout, qa_bout, cat + Dd, 1024, Dd, Dd, Dd, DPn, 0, stream); // qs slice
  wmean_k<<<(Bn * NST * An * TSn + 255) / 256, 256, 0, stream>>>(S2, wmean);
  qv_k<<<dim3(1024, (Dd + 255) / 256), 256, 0, stream>>>(wmean, vatt, cat);       // qv slice

  // ---- phase C: pre-MLP + GRU input gates (preh@kregion, gi@vregion) ----
  float* preh = kregion;
  float* gi   = vregion;
  gemm_f(cat, pre_w1, pre_b1, preh, 1024, DPn, DPn, DPn, DPn, 1, stream);
  gemm_f(preh, pre_w2, pre_b2, inp_s, 1024, Dd, DPn, DPn, Dd, 0, stream);
  gemm_f(inp_s, gru_wih, gru_bih, gi, 1024, GSn, Dd, Dd, GSn, 0, stream);

  // ---- sequential scan tail ----
  state_init<<<(Bn * Dd + 255) / 256, 256, 0, stream>>>(state0, state);
  for (int s = 0; s < NST; s++) {
    gemm_f(state, gru_whh, gru_bhh, gh, Bn, GSn, Dd, Dd, GSn, 0, stream);
    gru_combine<<<(Bn * An * Dd + 255) / 256, 256, 0, stream>>>(gi, gh, state, hbuf, s);
    gemm_f(hbuf, proj_w1, proj_b1, phb, Bn * An, Dd, Dd, Dd, Dd, 1, stream);
    tail_k<<<Bn, 256, 0, stream>>>(phb, proj_w2, proj_b2, inp_s, state,
                                   (outT*)d_out, s);
  }
}

// Round 4
// 1978.163 us; speedup vs baseline: 2.0065x; 2.0065x over previous
//
#include <hip/hip_runtime.h>
#include <hip/hip_bf16.h>
#include <math.h>

// ---- problem constants ----
constexpr int Dd  = 768;
constexpr int NH  = 12;
constexpr int DHd = 64;
constexpr int Bn  = 8;
constexpr int TVn = 512;
constexpr int TSn = 128;
constexpr int NST = 8;
constexpr int An  = 16;
constexpr int DPn = 3072;
constexpr int GSn = 2304;

using short8   = __attribute__((ext_vector_type(8))) short;   // 8 bf16 (4 VGPRs)
using floatx16 = __attribute__((ext_vector_type(16))) float;  // mfma 32x32 acc

__device__ inline unsigned short f2bf(float x) {
  union { float f; unsigned u; } a; a.f = x;
  unsigned r = (a.u + 0x7fffu + ((a.u >> 16) & 1u)) >> 16;
  return (unsigned short)r;
}
__device__ inline float bf2f(unsigned short h) {
  union { unsigned u; float f; } a; a.u = ((unsigned)h) << 16;
  return a.f;
}

// ---------------------------------------------------------------------------
// split f32 -> bf16 hi + bf16 lo (x ~= hi + lo, rel err ~2^-17)
// ---------------------------------------------------------------------------
__global__ void split_k(const float* __restrict__ x, unsigned short* __restrict__ h,
                        unsigned short* __restrict__ l, int n) {
  int i = blockIdx.x * 256 + threadIdx.x;
  if (i >= n) return;
  float v = x[i];
  unsigned short hb = f2bf(v);
  h[i] = hb;
  l[i] = f2bf(v - bf2f(hb));
}

// ---------------------------------------------------------------------------
// bf16x3 MFMA NT GEMM: C[M,N] = (Ah+Al)[M,K] @ (Bh+Bl)[N,K]^T + bias.
// M,N multiples of 64; K multiple of 32. 64x64 tile, 256 thr (4 waves,
// one 32x32 mfma quadrant each), 3 independent acc chains.
// ---------------------------------------------------------------------------
__device__ inline short8 lds8(const unsigned short* p) {
  const uint2* q = (const uint2*)p;
  uint2 a = q[0], b = q[1];
  union { unsigned u[4]; short8 v; } t;
  t.u[0] = a.x; t.u[1] = a.y; t.u[2] = b.x; t.u[3] = b.y;
  return t.v;
}

__global__ __launch_bounds__(256) void mfma_nt(
    const unsigned short* __restrict__ Ah, const unsigned short* __restrict__ Al, int lda,
    const unsigned short* __restrict__ Bh, const unsigned short* __restrict__ Bl,
    const float* __restrict__ bias,
    float* __restrict__ Cf, int ldc,
    unsigned short* __restrict__ Ch, unsigned short* __restrict__ Cl, int ldch,
    int K, int relu) {
  __shared__ unsigned short Ash[64][36], Asl[64][36], Bsh[64][36], Bsl[64][36];
  const int tid = threadIdx.x;
  const int bm = blockIdx.y * 64, bn = blockIdx.x * 64;
  const int wave = tid >> 6, lane = tid & 63;
  const int mh = (wave & 1) * 32, nh = (wave >> 1) * 32;
  const int l31 = lane & 31, hi5 = lane >> 5;
  const int srow = tid >> 2;         // 0..63
  const int skc  = (tid & 3) * 8;    // 0,8,16,24

  floatx16 acc_hh, acc_hl, acc_lh;
#pragma unroll
  for (int i = 0; i < 16; i++) { acc_hh[i] = 0.f; acc_hl[i] = 0.f; acc_lh[i] = 0.f; }

  for (int k0 = 0; k0 < K; k0 += 32) {
    uint4 a_h = *(const uint4*)(Ah + (size_t)(bm + srow) * lda + k0 + skc);
    uint4 a_l = *(const uint4*)(Al + (size_t)(bm + srow) * lda + k0 + skc);
    uint4 b_h = *(const uint4*)(Bh + (size_t)(bn + srow) * K + k0 + skc);
    uint4 b_l = *(const uint4*)(Bl + (size_t)(bn + srow) * K + k0 + skc);
    __syncthreads();  // previous iteration's reads done before overwrite
    *(uint2*)&Ash[srow][skc]     = make_uint2(a_h.x, a_h.y);
    *(uint2*)&Ash[srow][skc + 4] = make_uint2(a_h.z, a_h.w);
    *(uint2*)&Asl[srow][skc]     = make_uint2(a_l.x, a_l.y);
    *(uint2*)&Asl[srow][skc + 4] = make_uint2(a_l.z, a_l.w);
    *(uint2*)&Bsh[srow][skc]     = make_uint2(b_h.x, b_h.y);
    *(uint2*)&Bsh[srow][skc + 4] = make_uint2(b_h.z, b_h.w);
    *(uint2*)&Bsl[srow][skc]     = make_uint2(b_l.x, b_l.y);
    *(uint2*)&Bsl[srow][skc + 4] = make_uint2(b_l.z, b_l.w);
    __syncthreads();
#pragma unroll
    for (int ks = 0; ks < 32; ks += 16) {
      short8 fa_h = lds8(&Ash[mh + l31][ks + hi5 * 8]);
      short8 fa_l = lds8(&Asl[mh + l31][ks + hi5 * 8]);
      short8 fb_h = lds8(&Bsh[nh + l31][ks + hi5 * 8]);
      short8 fb_l = lds8(&Bsl[nh + l31][ks + hi5 * 8]);
      acc_hh = __builtin_amdgcn_mfma_f32_32x32x16_bf16(fa_h, fb_h, acc_hh, 0, 0, 0);
      acc_hl = __builtin_amdgcn_mfma_f32_32x32x16_bf16(fa_h, fb_l, acc_hl, 0, 0, 0);
      acc_lh = __builtin_amdgcn_mfma_f32_32x32x16_bf16(fa_l, fb_h, acc_lh, 0, 0, 0);
    }
  }
#pragma unroll
  for (int r = 0; r < 16; r++) {
    int m = bm + mh + (r & 3) + 8 * (r >> 2) + 4 * hi5;
    int n = bn + nh + l31;
    float v = acc_hh[r] + acc_hl[r] + acc_lh[r] + bias[n];
    if (relu) v = fmaxf(v, 0.f);
    if (Cf) Cf[(size_t)m * ldc + n] = v;
    if (Ch) {
      unsigned short hb = f2bf(v);
      Ch[(size_t)m * ldch + n] = hb;
      Cl[(size_t)m * ldch + n] = f2bf(v - bf2f(hb));
    }
  }
}

// ---------------------------------------------------------------------------
// scalar f32 NT GEMM (small M cases: question, gru gh)
// ---------------------------------------------------------------------------
__global__ __launch_bounds__(256) void gemm_s(const float* __restrict__ A,
                                              const float* __restrict__ Bw,
                                              const float* __restrict__ bias,
                                              float* __restrict__ C,
                                              int M, int N, int K,
                                              int lda, int ldc, int relu) {
  __shared__ float As[16][65];
  __shared__ float Bs[16][65];
  int bm = blockIdx.y * 64, bn = blockIdx.x * 64;
  int tid = threadIdx.x;
  int tx = tid & 15, ty = tid >> 4;
  float acc[4][4] = {};
  for (int k0 = 0; k0 < K; k0 += 16) {
#pragma unroll
    for (int i = 0; i < 4; i++) {
      int l = tid * 4 + i;
      int row = l >> 4, kk = l & 15;
      float v = 0.f;
      if (bm + row < M) v = A[(size_t)(bm + row) * lda + k0 + kk];
      As[kk][row] = v;
    }
#pragma unroll
    for (int i = 0; i < 4; i++) {
      int l = tid * 4 + i;
      int row = l >> 4, kk = l & 15;
      float v = 0.f;
      if (bn + row < N) v = Bw[(size_t)(bn + row) * K + k0 + kk];
      Bs[kk][row] = v;
    }
    __syncthreads();
#pragma unroll
    for (int kk = 0; kk < 16; kk++) {
      float a4[4], b4[4];
#pragma unroll
      for (int i = 0; i < 4; i++) a4[i] = As[kk][ty * 4 + i];
#pragma unroll
      for (int j = 0; j < 4; j++) b4[j] = Bs[kk][tx * 4 + j];
#pragma unroll
      for (int i = 0; i < 4; i++)
#pragma unroll
        for (int j = 0; j < 4; j++) acc[i][j] += a4[i] * b4[j];
    }
    __syncthreads();
  }
#pragma unroll
  for (int i = 0; i < 4; i++) {
    int m = bm + ty * 4 + i;
    if (m >= M) continue;
#pragma unroll
    for (int j = 0; j < 4; j++) {
      int n = bn + tx * 4 + j;
      if (n >= N) continue;
      float v = acc[i][j] + bias[n];
      if (relu) v = fmaxf(v, 0.f);
      C[(size_t)m * ldc + n] = v;
    }
  }
}

// ---------------------------------------------------------------------------
// attention kernels (f32) — unchanged from round 3
// ---------------------------------------------------------------------------
__global__ __launch_bounds__(256) void att_qk(const float* __restrict__ qp,
                                              const float* __restrict__ kp,
                                              float* __restrict__ Sout,
                                              int Tq, int Tk, int kdiv, float scale) {
  int g = blockIdx.x;
  int h = g % NH;
  int qrow0 = (g / NH) * Tq;
  int krow0 = (g / (NH * kdiv)) * Tk;
  int q0 = blockIdx.y * 32;
  int k0 = blockIdx.z * 64;
  __shared__ float Qs[32][DHd + 1];
  __shared__ float Ks[64][DHd + 1];
  int tid = threadIdx.x;
  {
    int row = tid >> 3, db = (tid & 7) * 8;
    int qr = q0 + row;
#pragma unroll
    for (int i = 0; i < 8; i++) {
      float v = 0.f;
      if (qr < Tq) v = qp[(size_t)(qrow0 + qr) * Dd + h * DHd + db + i];
      Qs[row][db + i] = v;
    }
  }
#pragma unroll
  for (int half = 0; half < 2; half++) {
    int row = (tid >> 3) + half * 32, db = (tid & 7) * 8;
    int kr = k0 + row;
#pragma unroll
    for (int i = 0; i < 8; i++) {
      float v = 0.f;
      if (kr < Tk) v = kp[(size_t)(krow0 + kr) * Dd + h * DHd + db + i];
      Ks[row][db + i] = v;
    }
  }
  __syncthreads();
  int q = tid >> 3, kg = tid & 7;
  float acc[8] = {};
  for (int d = 0; d < DHd; d++) {
    float qv = Qs[q][d];
#pragma unroll
    for (int j = 0; j < 8; j++) acc[j] += qv * Ks[kg * 8 + j][d];
  }
  if (q0 + q < Tq) {
    size_t base = ((size_t)g * Tq + q0 + q) * Tk + k0 + kg * 8;
#pragma unroll
    for (int j = 0; j < 8; j++) Sout[base + j] = acc[j] * scale;
  }
}

__global__ __launch_bounds__(256) void att_pv(const float* __restrict__ P,
                                              const float* __restrict__ vp,
                                              float* __restrict__ Out,
                                              int Tq, int Tk, int kdiv) {
  int g = blockIdx.x;
  int h = g % NH;
  int qrow0 = (g / NH) * Tq;
  int krow0 = (g / (NH * kdiv)) * Tk;
  int q0 = blockIdx.y * 32;
  __shared__ float Ps[32][65];
  __shared__ float Vs[64][DHd + 1];
  int tid = threadIdx.x;
  int q = tid >> 3, dg = tid & 7;
  float acc[8] = {};
  for (int k0 = 0; k0 < Tk; k0 += 64) {
    {
      int row = tid >> 3, cb = (tid & 7) * 8;
      int qr = q0 + row;
#pragma unroll
      for (int i = 0; i < 8; i++) {
        float v = 0.f;
        if (qr < Tq) v = P[((size_t)g * Tq + qr) * Tk + k0 + cb + i];
        Ps[row][cb + i] = v;
      }
    }
#pragma unroll
    for (int half = 0; half < 2; half++) {
      int row = (tid >> 3) + half * 32, db = (tid & 7) * 8;
#pragma unroll
      for (int i = 0; i < 8; i++)
        Vs[row][db + i] = vp[(size_t)(krow0 + k0 + row) * Dd + h * DHd + db + i];
    }
    __syncthreads();
    for (int kk = 0; kk < 64; kk++) {
      float p = Ps[q][kk];
#pragma unroll
      for (int j = 0; j < 8; j++) acc[j] += p * Vs[kk][dg * 8 + j];
    }
    __syncthreads();
  }
  if (q0 + q < Tq) {
    size_t base = (size_t)(qrow0 + q0 + q) * Dd + h * DHd + dg * 8;
#pragma unroll
    for (int j = 0; j < 8; j++) Out[base + j] = acc[j];
  }
}

__global__ __launch_bounds__(256) void softmax_rows(float* __restrict__ X, int len) {
  int row = blockIdx.x;
  float* p = X + (size_t)row * len;
  int tid = threadIdx.x;
  __shared__ float red[4];
  __shared__ float red2[4];
  float lmax = -1e30f;
  for (int j = tid; j < len; j += 256) lmax = fmaxf(lmax, p[j]);
  for (int off = 32; off; off >>= 1) lmax = fmaxf(lmax, __shfl_down(lmax, off));
  if ((tid & 63) == 0) red[tid >> 6] = lmax;
  __syncthreads();
  if (tid == 0) red[0] = fmaxf(fmaxf(red[0], red[1]), fmaxf(red[2], red[3]));
  __syncthreads();
  float m = red[0];
  float lsum = 0.f;
  for (int j = tid; j < len; j += 256) {
    float e = expf(p[j] - m);
    p[j] = e;
    lsum += e;
  }
  for (int off = 32; off; off >>= 1) lsum += __shfl_down(lsum, off);
  if ((tid & 63) == 0) red2[tid >> 6] = lsum;
  __syncthreads();
  if (tid == 0) red2[0] = red2[0] + red2[1] + red2[2] + red2[3];
  __syncthreads();
  float inv = 1.f / red2[0];
  for (int j = tid; j < len; j += 256) p[j] *= inv;
}

__global__ void wmean_k(const float* __restrict__ S2, float* __restrict__ W) {
  int idx = blockIdx.x * 256 + threadIdx.x;
  if (idx >= Bn * NST * An * TSn) return;
  int k = idx % TSn;
  int rest = idx / TSn;
  int a = rest % An;
  int bs = rest / An;
  float acc = 0.f;
  for (int h = 0; h < NH; h++)
    acc += S2[(((size_t)bs * NH + h) * An + a) * TSn + k];
  W[idx] = acc * (1.f / NH);
}

// qa = qf[b] + at[row]; split into cat slice [2D,3D)
__global__ void qa_add(const float* __restrict__ qf, const float* __restrict__ at,
                       unsigned short* __restrict__ ch, unsigned short* __restrict__ cl) {
  int idx = blockIdx.x * 256 + threadIdx.x;
  if (idx >= Bn * NST * An * Dd) return;
  int b = idx / (NST * An * Dd);
  int row = idx / Dd;
  int j = idx % Dd;
  float v = qf[b * Dd + j] + at[idx];
  size_t o = (size_t)row * DPn + 2 * Dd + j;
  unsigned short hb = f2bf(v);
  ch[o] = hb; cl[o] = f2bf(v - bf2f(hb));
}

// qv = W @ vatt; split into cat slice [0,D)
__global__ __launch_bounds__(256) void qv_k(const float* __restrict__ W,
                                            const float* __restrict__ vatt,
                                            unsigned short* __restrict__ ch,
                                            unsigned short* __restrict__ cl) {
  int row = blockIdx.x;
  int j = blockIdx.y * 256 + threadIdx.x;
  if (j >= Dd) return;
  int b = row / (NST * An);
  float acc = 0.f;
  for (int k = 0; k < TSn; k++)
    acc += W[(size_t)row * TSn + k] * vatt[((size_t)b * TSn + k) * Dd + j];
  size_t o = (size_t)row * DPn + j;
  unsigned short hb = f2bf(acc);
  ch[o] = hb; cl[o] = f2bf(acc - bf2f(hb));
}

__global__ void state_init(const float* __restrict__ s0, float* __restrict__ state) {
  int idx = blockIdx.x * 256 + threadIdx.x;
  if (idx >= Bn * Dd) return;
  state[idx] = s0[idx % Dd];
}

__global__ void gru_combine(const float* __restrict__ gi, const float* __restrict__ gh,
                            const float* __restrict__ state, float* __restrict__ hout, int s) {
  int idx = blockIdx.x * 256 + threadIdx.x;
  if (idx >= Bn * An * Dd) return;
  int j = idx % Dd;
  int r = idx / Dd;
  int b = r / An;
  int a = r % An;
  size_t girow = ((size_t)(b * NST + s) * An + a);
  const float* gip = gi + girow * GSn;
  const float* ghp = gh + (size_t)b * GSn;
  float ir = gip[j], iz = gip[Dd + j], inn = gip[2 * Dd + j];
  float hr = ghp[j], hz = ghp[Dd + j], hn = ghp[2 * Dd + j];
  float rg = 1.f / (1.f + expf(-(ir + hr)));
  float zg = 1.f / (1.f + expf(-(iz + hz)));
  float ng = tanhf(inn + rg * hn);
  float st = state[b * Dd + j];
  hout[idx] = (1.f - zg) * ng + zg * st;
}

__global__ __launch_bounds__(256) void tail_k(const float* __restrict__ ph,
                                              const float* __restrict__ pw2,
                                              const float* __restrict__ pb2,
                                              const float* __restrict__ inp_s,
                                              float* __restrict__ state,
                                              float* __restrict__ out, int s) {
  int b = blockIdx.x;
  int tid = threadIdx.x;
  int wave = tid >> 6, lane = tid & 63;
  __shared__ float slog[An];
  __shared__ int samax;
  for (int a = wave; a < An; a += 4) {
    const float* row = ph + (size_t)(b * An + a) * Dd;
    float acc = 0.f;
    for (int j = lane; j < Dd; j += 64) acc += row[j] * pw2[j];
    for (int off = 32; off; off >>= 1) acc += __shfl_down(acc, off);
    if (lane == 0) slog[a] = acc + pb2[0];
  }
  __syncthreads();
  if (tid == 0) {
    float best = slog[0];
    int bi = 0;
    for (int a = 1; a < An; a++)
      if (slog[a] > best) { best = slog[a]; bi = a; }
    samax = bi;
  }
  __syncthreads();
  if (tid < An) out[(size_t)(b * NST + s) * An + tid] = slog[tid];
  int am = samax;
  size_t srow = ((size_t)(b * NST + s) * An + am) * (size_t)Dd;
  for (int j = tid; j < Dd; j += 256) state[b * Dd + j] = inp_s[srow + j];
}

// ---------------------------------------------------------------------------
// host helpers
// ---------------------------------------------------------------------------
typedef unsigned short us;

static inline void split(const float* x, us* h, us* l, int n, hipStream_t st) {
  split_k<<<(n + 255) / 256, 256, 0, st>>>(x, h, l, n);
}
static inline void mm(const us* Ah, const us* Al, int lda, const us* Bh, const us* Bl,
                      const float* bias, float* Cf, int ldc, us* Ch, us* Cl, int ldch,
                      int M, int N, int K, int relu, hipStream_t st) {
  dim3 g(N / 64, M / 64);
  mfma_nt<<<g, 256, 0, st>>>(Ah, Al, lda, Bh, Bl, bias, Cf, ldc, Ch, Cl, ldch, K, relu);
}
static inline void sgemm(const float* A, const float* W, const float* bias, float* C,
                         int M, int N, int K, int lda, int ldc, int relu, hipStream_t st) {
  dim3 g((N + 63) / 64, (M + 63) / 64);
  gemm_s<<<g, 256, 0, st>>>(A, W, bias, C, M, N, K, lda, ldc, relu);
}

extern "C" void kernel_launch(void* const* d_in, const int* in_sizes, int n_in,
                              void* d_out, int out_size, void* d_ws, size_t ws_size,
                              hipStream_t stream) {
  const float* video     = (const float*)d_in[0];
  const float* script    = (const float*)d_in[1];
  const float* question  = (const float*)d_in[2];
  const float* a_texts   = (const float*)d_in[3];
  const float* a_buttons = (const float*)d_in[4];
  const float* v_w1 = (const float*)d_in[5];
  const float* v_b1 = (const float*)d_in[6];
  const float* v_w2 = (const float*)d_in[7];
  const float* v_b2 = (const float*)d_in[8];
  const float* t_w1 = (const float*)d_in[9];
  const float* t_b1 = (const float*)d_in[10];
  const float* t_w2 = (const float*)d_in[11];
  const float* t_b2 = (const float*)d_in[12];
  const float* pre_w1 = (const float*)d_in[13];
  const float* pre_b1 = (const float*)d_in[14];
  const float* pre_w2 = (const float*)d_in[15];
  const float* pre_b2 = (const float*)d_in[16];
  const float* s2v_win  = (const float*)d_in[17];
  const float* s2v_bin  = (const float*)d_in[18];
  const float* s2v_wout = (const float*)d_in[19];
  const float* s2v_bout = (const float*)d_in[20];
  const float* qa_win  = (const float*)d_in[21];
  const float* qa_bin  = (const float*)d_in[22];
  const float* qa_wout = (const float*)d_in[23];
  const float* qa_bout = (const float*)d_in[24];
  const float* gru_wih = (const float*)d_in[25];
  const float* gru_whh = (const float*)d_in[26];
  const float* gru_bih = (const float*)d_in[27];
  const float* gru_bhh = (const float*)d_in[28];
  const float* proj_w1 = (const float*)d_in[29];
  const float* proj_b1 = (const float*)d_in[30];
  const float* proj_w2 = (const float*)d_in[31];
  const float* proj_b2 = (const float*)d_in[32];
  const float* state0  = (const float*)d_in[33];
  (void)in_sizes; (void)n_in; (void)out_size; (void)ws_size;

  // element counts
  constexpr int W589  = 768 * 768;
  constexpr int W1769 = 2304 * 768;
  constexpr int W9437 = 3072 * 3072;
  constexpr int W2359 = 768 * 3072;
  constexpr int SMe   = 1024 * 768;
  constexpr int BIGe  = 4096 * 768;

  // ---- region layout (bytes), ~100 MB total, lifetime-overlaid ----
  char* base = (char*)d_ws;
  char* RW1 = base;                   // 9,437,184  : phase-A weight splits
  char* RW2 = RW1 + 9437184;          // 9,437,184  : s2v w -> qa w -> pre_w2
  char* R1  = RW2 + 9437184;          // 28,311,552 : vid/hid -> kqv f32 -> qa bufs -> pre_w1(spans R2) -> gru w
  char* R2  = R1 + 28311552;          // 12,582,912 : v h/l -> attnout/ao -> ao2 -> (pre_w1 tail)
  char* X   = R2 + 12582912;          // 25,165,824 : S1 -> cat h/l + preh h/l -> gi
  char* P   = X + 25165824;           // ~20 MB persistents

  // RW1
  us* vw1h = (us*)RW1;            us* vw1l = vw1h + W589;
  us* vw2h = vw1l + W589;         us* vw2l = vw2h + W589;
  us* tw1h = vw2l + W589;         us* tw1l = tw1h + W589;
  us* tw2h = tw1l + W589;         us* tw2l = tw2h + W589;
  // RW2 (sequential reuse)
  us* s2vwh = (us*)RW2;           us* s2vwl = s2vwh + W1769;
  us* s2voh = s2vwl + W1769;      us* s2vol = s2voh + W589;
  us* qawh  = (us*)RW2;           us* qawl  = qawh + W1769;
  us* qaoh  = qawl + W1769;       us* qaol  = qaoh + W589;
  us* pw2h  = (us*)RW2;           us* pw2l  = pw2h + W2359;
  // R1 phase A
  us* vidh = (us*)R1;             us* vidl = vidh + BIGe;
  us* hidh = vidl + BIGe;         us* hidl = hidh + BIGe;
  us* scrh = (us*)R1;             us* scrl = scrh + SMe;   // overlays dead vid (after video GEMM1)
  // R1 attention
  float* kproj = (float*)R1;
  float* vproj = kproj + BIGe;
  float* qproj = vproj + BIGe;
  // R1 qa phase
  float* kp2   = (float*)R1;
  float* vp2   = kp2 + SMe;
  float* qp2   = vp2 + SMe;
  float* S2    = qp2 + SMe;                      // 1,572,864 f
  float* wmean = S2 + (size_t)Bn * NST * NH * An * TSn;  // 131,072 f
  us* abhh = (us*)(R1 + 16515072); us* abhl = abhh + SMe;
  // R1(+R2) pre
  us* pw1h = (us*)R1;             us* pw1l = pw1h + W9437;  // spans into R2
  // R1 gru/proj weights
  us* gwihh = (us*)R1;            us* gwihl = gwihh + W1769;
  us* pjw1h = (us*)(R1 + 7077888); us* pjw1l = pjw1h + W589;
  // R2
  us* vh = (us*)R2;               us* vl = vh + BIGe;
  float* attnout = (float*)R2;                       // after v dead
  us* aoh = (us*)(R2 + 3145728);  us* aol = aoh + SMe;
  // X
  float* S1 = (float*)X;
  us* cath = (us*)X;              us* catl = cath + (size_t)1024 * DPn;
  us* prehh = (us*)(X + 12582912); us* prehl = prehh + (size_t)1024 * DPn;
  float* gi = (float*)X;          // after cat dead
  // P
  us* abinh = (us*)P;             us* abinl = abinh + SMe;
  us* sch   = abinl + SMe;        us* scl   = sch + SMe;
  float* at_f   = (float*)(P + 6291456);
  float* vatt   = (float*)(P + 9437184);
  float* inps_f = (float*)(P + 12582912);
  us* inpsh = (us*)(P + 15728640); us* inpsl = inpsh + SMe;
  float* qf    = (float*)(P + 18874368);
  float* qhid  = (float*)(P + 18898944);
  float* state = (float*)(P + 18923520);
  float* gh    = (float*)(P + 18948096);
  float* hbuf  = (float*)(P + 19021824);
  us* hbufh = (us*)(P + 19415040); us* hbufl = hbufh + Bn * An * Dd;
  float* phb   = (float*)(P + 19808256);

  // ---- phase A: MLPs via bf16x3 MFMA ----
  split(video, vidh, vidl, BIGe, stream);
  split(v_w1, vw1h, vw1l, W589, stream);
  split(v_w2, vw2h, vw2l, W589, stream);
  split(t_w1, tw1h, tw1l, W589, stream);
  split(t_w2, tw2h, tw2l, W589, stream);
  mm(vidh, vidl, Dd, vw1h, vw1l, v_b1, nullptr, 0, hidh, hidl, Dd, 4096, Dd, Dd, 1, stream);
  mm(hidh, hidl, Dd, vw2h, vw2l, v_b2, nullptr, 0, vh, vl, Dd, 4096, Dd, Dd, 0, stream);
  split(script, scrh, scrl, SMe, stream);
  mm(scrh, scrl, Dd, tw1h, tw1l, t_b1, nullptr, 0, hidh, hidl, Dd, 1024, Dd, Dd, 1, stream);
  mm(hidh, hidl, Dd, tw2h, tw2l, t_b2, nullptr, 0, sch, scl, Dd, 1024, Dd, Dd, 0, stream);
  sgemm(question, t_w1, t_b1, qhid, Bn, Dd, Dd, Dd, Dd, 1, stream);
  sgemm(qhid, t_w2, t_b2, qf, Bn, Dd, Dd, Dd, Dd, 0, stream);
  split(a_texts, scrh, scrl, SMe, stream);
  mm(scrh, scrl, Dd, tw1h, tw1l, t_b1, nullptr, 0, hidh, hidl, Dd, 1024, Dd, Dd, 1, stream);
  mm(hidh, hidl, Dd, tw2h, tw2l, t_b2, at_f, Dd, nullptr, nullptr, 0, 1024, Dd, Dd, 0, stream);
  split(a_buttons, abinh, abinl, SMe, stream);

  // ---- s2v attention ----
  split(s2v_win, s2vwh, s2vwl, W1769, stream);
  split(s2v_wout, s2voh, s2vol, W589, stream);
  mm(vh, vl, Dd, s2vwh + (size_t)Dd * Dd, s2vwl + (size_t)Dd * Dd, s2v_bin + Dd,
     kproj, Dd, nullptr, nullptr, 0, 4096, Dd, Dd, 0, stream);
  mm(vh, vl, Dd, s2vwh + 2 * (size_t)Dd * Dd, s2vwl + 2 * (size_t)Dd * Dd, s2v_bin + 2 * Dd,
     vproj, Dd, nullptr, nullptr, 0, 4096, Dd, Dd, 0, stream);
  mm(sch, scl, Dd, s2vwh, s2vwl, s2v_bin, qproj, Dd, nullptr, nullptr, 0, 1024, Dd, Dd, 0, stream);
  att_qk<<<dim3(Bn * NH, TSn / 32, TVn / 64), 256, 0, stream>>>(qproj, kproj, S1, TSn, TVn, 1, 0.125f);
  softmax_rows<<<Bn * NH * TSn, 256, 0, stream>>>(S1, TVn);
  att_pv<<<dim3(Bn * NH, TSn / 32), 256, 0, stream>>>(S1, vproj, attnout, TSn, TVn, 1);
  split(attnout, aoh, aol, SMe, stream);
  mm(aoh, aol, Dd, s2voh, s2vol, s2v_bout, vatt, Dd, nullptr, nullptr, 0, 1024, Dd, Dd, 0, stream);

  // ---- phase B: ab MLP -> cat slice, qa attention ----
  mm(abinh, abinl, Dd, vw1h, vw1l, v_b1, nullptr, 0, abhh, abhl, Dd, 1024, Dd, Dd, 1, stream);
  mm(abhh, abhl, Dd, vw2h, vw2l, v_b2, nullptr, 0, cath + 3 * Dd, catl + 3 * Dd, DPn,
     1024, Dd, Dd, 0, stream);
  qa_add<<<(1024 * Dd + 255) / 256, 256, 0, stream>>>(qf, at_f, cath, catl);
  split(qa_win, qawh, qawl, W1769, stream);
  split(qa_wout, qaoh, qaol, W589, stream);
  mm(sch, scl, Dd, qawh + (size_t)Dd * Dd, qawl + (size_t)Dd * Dd, qa_bin + Dd,
     kp2, Dd, nullptr, nullptr, 0, 1024, Dd, Dd, 0, stream);
  mm(sch, scl, Dd, qawh + 2 * (size_t)Dd * Dd, qawl + 2 * (size_t)Dd * Dd, qa_bin + 2 * Dd,
     vp2, Dd, nullptr, nullptr, 0, 1024, Dd, Dd, 0, stream);
  mm(cath + 2 * Dd, catl + 2 * Dd, DPn, qawh, qawl, qa_bin, qp2, Dd, nullptr, nullptr, 0,
     1024, Dd, Dd, 0, stream);
  att_qk<<<dim3(Bn * NST * NH, 1, TSn / 64), 256, 0, stream>>>(qp2, kp2, S2, An, TSn, NST, 0.125f);
  softmax_rows<<<Bn * NST * NH * An, 256, 0, stream>>>(S2, TSn);
  att_pv<<<dim3(Bn * NST * NH, 1), 256, 0, stream>>>(S2, vp2, attnout, An, TSn, NST);
  split(attnout, aoh, aol, SMe, stream);
  mm(aoh, aol, Dd, qaoh, qaol, qa_bout, nullptr, 0, cath + Dd, catl + Dd, DPn,
     1024, Dd, Dd, 0, stream);
  wmean_k<<<(Bn * NST * An * TSn + 255) / 256, 256, 0, stream>>>(S2, wmean);
  qv_k<<<dim3(1024, (Dd + 255) / 256), 256, 0, stream>>>(wmean, vatt, cath, catl);

  // ---- pre-MLP + GRU input gates ----
  split(pre_w1, pw1h, pw1l, W9437, stream);
  mm(cath, catl, DPn, pw1h, pw1l, pre_b1, nullptr, 0, prehh, prehl, DPn,
     1024, DPn, DPn, 1, stream);
  split(pre_w2, pw2h, pw2l, W2359, stream);
  mm(prehh, prehl, DPn, pw2h, pw2l, pre_b2, inps_f, Dd, inpsh, inpsl, Dd,
     1024, Dd, DPn, 0, stream);
  split(gru_wih, gwihh, gwihl, W1769, stream);
  split(proj_w1, pjw1h, pjw1l, W589, stream);
  mm(inpsh, inpsl, Dd, gwihh, gwihl, gru_bih, gi, GSn, nullptr, nullptr, 0,
     1024, GSn, Dd, 0, stream);

  // ---- sequential scan tail ----
  state_init<<<(Bn * Dd + 255) / 256, 256, 0, stream>>>(state0, state);
  for (int s = 0; s < NST; s++) {
    sgemm(state, gru_whh, gru_bhh, gh, Bn, GSn, Dd, Dd, GSn, 0, stream);
    gru_combine<<<(Bn * An * Dd + 255) / 256, 256, 0, stream>>>(gi, gh, state, hbuf, s);
    split(hbuf, hbufh, hbufl, Bn * An * Dd, stream);
    mm(hbufh, hbufl, Dd, pjw1h, pjw1l, proj_b1, phb, Dd, nullptr, nullptr, 0,
       Bn * An, Dd, Dd, 1, stream);
    tail_k<<<Bn, 256, 0, stream>>>(phb, proj_w2, proj_b2, inps_f, state, (float*)d_out, s);
  }
}

// Round 5
// 1788.448 us; speedup vs baseline: 2.2193x; 1.1061x over previous
//
#include <hip/hip_runtime.h>
#include <hip/hip_bf16.h>
#include <math.h>

constexpr int Dd  = 768;
constexpr int NH  = 12;
constexpr int DHd = 64;
constexpr int Bn  = 8;
constexpr int TVn = 512;
constexpr int TSn = 128;
constexpr int NST = 8;
constexpr int An  = 16;
constexpr int DPn = 3072;
constexpr int GSn = 2304;

typedef unsigned short us;
using short8   = __attribute__((ext_vector_type(8))) short;
using floatx4  = __attribute__((ext_vector_type(4))) float;
using floatx16 = __attribute__((ext_vector_type(16))) float;

__device__ inline us f2bf(float x) {
  union { float f; unsigned u; } a; a.f = x;
  return (us)((a.u + 0x7fffu + ((a.u >> 16) & 1u)) >> 16);
}
__device__ inline float bf2f(us h) {
  union { unsigned u; float f; } a; a.u = ((unsigned)h) << 16;
  return a.f;
}

// ---------------------------------------------------------------------------
// splits
// ---------------------------------------------------------------------------
__global__ void split_k(const float* __restrict__ x, us* __restrict__ h,
                        us* __restrict__ l, int n) {
  for (int i = blockIdx.x * 256 + threadIdx.x; i < n; i += gridDim.x * 256) {
    float v = x[i];
    us hb = f2bf(v);
    h[i] = hb;
    l[i] = f2bf(v - bf2f(hb));
  }
}

__global__ void split4_k(const float* s0, us* h0, us* l0, int n0,
                         const float* s1, us* h1, us* l1, int n1,
                         const float* s2, us* h2, us* l2, int n2,
                         const float* s3, us* h3, us* l3, int n3) {
  const float* s; us* h; us* l; int n;
  switch (blockIdx.y) {
    case 0: s = s0; h = h0; l = l0; n = n0; break;
    case 1: s = s1; h = h1; l = l1; n = n1; break;
    case 2: s = s2; h = h2; l = l2; n = n2; break;
    default: s = s3; h = h3; l = l3; n = n3; break;
  }
  for (int i = blockIdx.x * 256 + threadIdx.x; i < n; i += gridDim.x * 256) {
    float v = s[i];
    us hb = f2bf(v);
    h[i] = hb;
    l[i] = f2bf(v - bf2f(hb));
  }
}

// ---------------------------------------------------------------------------
// bf16x3 MFMA NT GEMM, double-buffered LDS, one barrier per K-iter.
// M,N mult of 64; K mult of 32. 64x64 tile, 4 waves.
// ---------------------------------------------------------------------------
__device__ inline short8 lds8(const us* p) {
  const uint2* q = (const uint2*)p;
  uint2 a = q[0], b = q[1];
  union { unsigned u[4]; short8 v; } t;
  t.u[0] = a.x; t.u[1] = a.y; t.u[2] = b.x; t.u[3] = b.y;
  return t.v;
}

__global__ __launch_bounds__(256) void mfma_nt(
    const us* __restrict__ Ah, const us* __restrict__ Al, int lda,
    const us* __restrict__ Bh, const us* __restrict__ Bl,
    const float* __restrict__ bias,
    float* __restrict__ Cf, int ldc,
    us* __restrict__ Ch, us* __restrict__ Cl, int ldch,
    int K, int relu) {
  __shared__ us Ash[2][64][36], Asl[2][64][36], Bsh[2][64][36], Bsl[2][64][36];
  const int tid = threadIdx.x;
  const int bm = blockIdx.y * 64, bn = blockIdx.x * 64;
  const int wave = tid >> 6, lane = tid & 63;
  const int mh = (wave & 1) * 32, nh = (wave >> 1) * 32;
  const int l31 = lane & 31, hi5 = lane >> 5;
  const int srow = tid >> 2, skc = (tid & 3) * 8;
  const us* pAh = Ah + (size_t)(bm + srow) * lda + skc;
  const us* pAl = Al + (size_t)(bm + srow) * lda + skc;
  const us* pBh = Bh + (size_t)(bn + srow) * K + skc;
  const us* pBl = Bl + (size_t)(bn + srow) * K + skc;

  floatx16 acc_hh, acc_hl, acc_lh;
#pragma unroll
  for (int i = 0; i < 16; i++) { acc_hh[i] = 0.f; acc_hl[i] = 0.f; acc_lh[i] = 0.f; }

  uint4 a_h = *(const uint4*)pAh;
  uint4 a_l = *(const uint4*)pAl;
  uint4 b_h = *(const uint4*)pBh;
  uint4 b_l = *(const uint4*)pBl;
  const int iters = K >> 5;
  int p = 0;
  for (int it = 0; it < iters; ++it) {
    *(uint2*)&Ash[p][srow][skc]     = make_uint2(a_h.x, a_h.y);
    *(uint2*)&Ash[p][srow][skc + 4] = make_uint2(a_h.z, a_h.w);
    *(uint2*)&Asl[p][srow][skc]     = make_uint2(a_l.x, a_l.y);
    *(uint2*)&Asl[p][srow][skc + 4] = make_uint2(a_l.z, a_l.w);
    *(uint2*)&Bsh[p][srow][skc]     = make_uint2(b_h.x, b_h.y);
    *(uint2*)&Bsh[p][srow][skc + 4] = make_uint2(b_h.z, b_h.w);
    *(uint2*)&Bsl[p][srow][skc]     = make_uint2(b_l.x, b_l.y);
    *(uint2*)&Bsl[p][srow][skc + 4] = make_uint2(b_l.z, b_l.w);
    __syncthreads();
    int knext = (it + 1 < iters) ? (it + 1) * 32 : 0;
    a_h = *(const uint4*)(pAh + knext);
    a_l = *(const uint4*)(pAl + knext);
    b_h = *(const uint4*)(pBh + knext);
    b_l = *(const uint4*)(pBl + knext);
#pragma unroll
    for (int ks = 0; ks < 32; ks += 16) {
      short8 fa_h = lds8(&Ash[p][mh + l31][ks + hi5 * 8]);
      short8 fa_l = lds8(&Asl[p][mh + l31][ks + hi5 * 8]);
      short8 fb_h = lds8(&Bsh[p][nh + l31][ks + hi5 * 8]);
      short8 fb_l = lds8(&Bsl[p][nh + l31][ks + hi5 * 8]);
      acc_hh = __builtin_amdgcn_mfma_f32_32x32x16_bf16(fa_h, fb_h, acc_hh, 0, 0, 0);
      acc_hl = __builtin_amdgcn_mfma_f32_32x32x16_bf16(fa_h, fb_l, acc_hl, 0, 0, 0);
      acc_lh = __builtin_amdgcn_mfma_f32_32x32x16_bf16(fa_l, fb_h, acc_lh, 0, 0, 0);
    }
    p ^= 1;
  }
#pragma unroll
  for (int r = 0; r < 16; r++) {
    int m = bm + mh + (r & 3) + 8 * (r >> 2) + 4 * hi5;
    int n = bn + nh + l31;
    float v = acc_hh[r] + acc_hl[r] + acc_lh[r] + bias[n];
    if (relu) v = fmaxf(v, 0.f);
    if (Cf) Cf[(size_t)m * ldc + n] = v;
    if (Ch) {
      us hb = f2bf(v);
      Ch[(size_t)m * ldch + n] = hb;
      Cl[(size_t)m * ldch + n] = f2bf(v - bf2f(hb));
    }
  }
}

// ---------------------------------------------------------------------------
// scalar f32 NT GEMM (tiny M: question, gh0)
// ---------------------------------------------------------------------------
__global__ __launch_bounds__(256) void gemm_s(const float* __restrict__ A,
                                              const float* __restrict__ Bw,
                                              const float* __restrict__ bias,
                                              float* __restrict__ C,
                                              int M, int N, int K,
                                              int lda, int ldc, int relu) {
  __shared__ float As[16][65];
  __shared__ float Bs[16][65];
  int bm = blockIdx.y * 64, bn = blockIdx.x * 64;
  int tid = threadIdx.x;
  int tx = tid & 15, ty = tid >> 4;
  float acc[4][4] = {};
  for (int k0 = 0; k0 < K; k0 += 16) {
#pragma unroll
    for (int i = 0; i < 4; i++) {
      int l = tid * 4 + i;
      int row = l >> 4, kk = l & 15;
      float v = 0.f;
      if (bm + row < M) v = A[(size_t)(bm + row) * lda + k0 + kk];
      As[kk][row] = v;
    }
#pragma unroll
    for (int i = 0; i < 4; i++) {
      int l = tid * 4 + i;
      int row = l >> 4, kk = l & 15;
      float v = 0.f;
      if (bn + row < N) v = Bw[(size_t)(bn + row) * K + k0 + kk];
      Bs[kk][row] = v;
    }
    __syncthreads();
#pragma unroll
    for (int kk = 0; kk < 16; kk++) {
      float a4[4], b4[4];
#pragma unroll
      for (int i = 0; i < 4; i++) a4[i] = As[kk][ty * 4 + i];
#pragma unroll
      for (int j = 0; j < 4; j++) b4[j] = Bs[kk][tx * 4 + j];
#pragma unroll
      for (int i = 0; i < 4; i++)
#pragma unroll
        for (int j = 0; j < 4; j++) acc[i][j] += a4[i] * b4[j];
    }
    __syncthreads();
  }
#pragma unroll
  for (int i = 0; i < 4; i++) {
    int m = bm + ty * 4 + i;
    if (m >= M) continue;
#pragma unroll
    for (int j = 0; j < 4; j++) {
      int n = bn + tx * 4 + j;
      if (n >= N) continue;
      float v = acc[i][j] + bias[n];
      if (relu) v = fmaxf(v, 0.f);
      C[(size_t)m * ldc + n] = v;
    }
  }
}

// ---------------------------------------------------------------------------
// attention (f32); ldk/ldv allow merged K/V buffers
// ---------------------------------------------------------------------------
__global__ __launch_bounds__(256) void att_qk(const float* __restrict__ qp,
                                              const float* __restrict__ kp,
                                              float* __restrict__ Sout,
                                              int Tq, int Tk, int kdiv, int ldk,
                                              float scale) {
  int g = blockIdx.x;
  int h = g % NH;
  int qrow0 = (g / NH) * Tq;
  int krow0 = (g / (NH * kdiv)) * Tk;
  int q0 = blockIdx.y * 32;
  int k0 = blockIdx.z * 64;
  __shared__ float Qs[32][DHd + 1];
  __shared__ float Ks[64][DHd + 1];
  int tid = threadIdx.x;
  {
    int row = tid >> 3, db = (tid & 7) * 8;
    int qr = q0 + row;
#pragma unroll
    for (int i = 0; i < 8; i++) {
      float v = 0.f;
      if (qr < Tq) v = qp[(size_t)(qrow0 + qr) * Dd + h * DHd + db + i];
      Qs[row][db + i] = v;
    }
  }
#pragma unroll
  for (int half = 0; half < 2; half++) {
    int row = (tid >> 3) + half * 32, db = (tid & 7) * 8;
    int kr = k0 + row;
#pragma unroll
    for (int i = 0; i < 8; i++) {
      float v = 0.f;
      if (kr < Tk) v = kp[(size_t)(krow0 + kr) * ldk + h * DHd + db + i];
      Ks[row][db + i] = v;
    }
  }
  __syncthreads();
  int q = tid >> 3, kg = tid & 7;
  float acc[8] = {};
  for (int d = 0; d < DHd; d++) {
    float qv = Qs[q][d];
#pragma unroll
    for (int j = 0; j < 8; j++) acc[j] += qv * Ks[kg * 8 + j][d];
  }
  if (q0 + q < Tq) {
    size_t base = ((size_t)g * Tq + q0 + q) * Tk + k0 + kg * 8;
#pragma unroll
    for (int j = 0; j < 8; j++) Sout[base + j] = acc[j] * scale;
  }
}

__global__ __launch_bounds__(256) void att_pv(const float* __restrict__ P,
                                              const float* __restrict__ vp,
                                              float* __restrict__ Out,
                                              int Tq, int Tk, int kdiv, int ldv) {
  int g = blockIdx.x;
  int h = g % NH;
  int qrow0 = (g / NH) * Tq;
  int krow0 = (g / (NH * kdiv)) * Tk;
  int q0 = blockIdx.y * 32;
  __shared__ float Ps[32][65];
  __shared__ float Vs[64][DHd + 1];
  int tid = threadIdx.x;
  int q = tid >> 3, dg = tid & 7;
  float acc[8] = {};
  for (int k0 = 0; k0 < Tk; k0 += 64) {
    {
      int row = tid >> 3, cb = (tid & 7) * 8;
      int qr = q0 + row;
#pragma unroll
      for (int i = 0; i < 8; i++) {
        float v = 0.f;
        if (qr < Tq) v = P[((size_t)g * Tq + qr) * Tk + k0 + cb + i];
        Ps[row][cb + i] = v;
      }
    }
#pragma unroll
    for (int half = 0; half < 2; half++) {
      int row = (tid >> 3) + half * 32, db = (tid & 7) * 8;
#pragma unroll
      for (int i = 0; i < 8; i++)
        Vs[row][db + i] = vp[(size_t)(krow0 + k0 + row) * ldv + h * DHd + db + i];
    }
    __syncthreads();
    for (int kk = 0; kk < 64; kk++) {
      float p = Ps[q][kk];
#pragma unroll
      for (int j = 0; j < 8; j++) acc[j] += p * Vs[kk][dg * 8 + j];
    }
    __syncthreads();
  }
  if (q0 + q < Tq) {
    size_t base = (size_t)(qrow0 + q0 + q) * Dd + h * DHd + dg * 8;
#pragma unroll
    for (int j = 0; j < 8; j++) Out[base + j] = acc[j];
  }
}

__global__ __launch_bounds__(256) void softmax_rows(float* __restrict__ X, int len) {
  int row = blockIdx.x;
  float* p = X + (size_t)row * len;
  int tid = threadIdx.x;
  __shared__ float red[4];
  __shared__ float red2[4];
  float lmax = -1e30f;
  for (int j = tid; j < len; j += 256) lmax = fmaxf(lmax, p[j]);
  for (int off = 32; off; off >>= 1) lmax = fmaxf(lmax, __shfl_down(lmax, off));
  if ((tid & 63) == 0) red[tid >> 6] = lmax;
  __syncthreads();
  if (tid == 0) red[0] = fmaxf(fmaxf(red[0], red[1]), fmaxf(red[2], red[3]));
  __syncthreads();
  float m = red[0];
  float lsum = 0.f;
  for (int j = tid; j < len; j += 256) {
    float e = expf(p[j] - m);
    p[j] = e;
    lsum += e;
  }
  for (int off = 32; off; off >>= 1) lsum += __shfl_down(lsum, off);
  if ((tid & 63) == 0) red2[tid >> 6] = lsum;
  __syncthreads();
  if (tid == 0) red2[0] = red2[0] + red2[1] + red2[2] + red2[3];
  __syncthreads();
  float inv = 1.f / red2[0];
  for (int j = tid; j < len; j += 256) p[j] *= inv;
}

// fused head-mean + qv = W @ vatt -> cat slice [0,D). one block per row.
__global__ __launch_bounds__(256) void qv2_k(const float* __restrict__ S2,
                                             const float* __restrict__ vatt,
                                             us* __restrict__ ch, us* __restrict__ cl) {
  int row = blockIdx.x;            // (b*NST+s)*An + a
  int b = row / (NST * An);
  int bs = row / An;
  int a = row % An;
  __shared__ float wm[TSn];
  int tid = threadIdx.x;
  if (tid < TSn) {
    float acc = 0.f;
    for (int h = 0; h < NH; h++)
      acc += S2[(((size_t)bs * NH + h) * An + a) * TSn + tid];
    wm[tid] = acc * (1.f / NH);
  }
  __syncthreads();
  for (int j = tid; j < Dd; j += 256) {
    float acc = 0.f;
    for (int k = 0; k < TSn; k++)
      acc += wm[k] * vatt[((size_t)b * TSn + k) * Dd + j];
    size_t o = (size_t)row * DPn + j;
    us hb = f2bf(acc);
    ch[o] = hb;
    cl[o] = f2bf(acc - bf2f(hb));
  }
}

// qa = qf[b] + at[row] -> cat slice [2D,3D)
__global__ void qa_add(const float* __restrict__ qf, const float* __restrict__ at,
                       us* __restrict__ ch, us* __restrict__ cl) {
  int idx = blockIdx.x * 256 + threadIdx.x;
  if (idx >= Bn * NST * An * Dd) return;
  int b = idx / (NST * An * Dd);
  int row = idx / Dd;
  int j = idx % Dd;
  float v = qf[b * Dd + j] + at[idx];
  size_t o = (size_t)row * DPn + 2 * Dd + j;
  us hb = f2bf(v);
  ch[o] = hb;
  cl[o] = f2bf(v - bf2f(hb));
}

// ---------------------------------------------------------------------------
// fused sequential scan: one block per batch item, 1024 threads (16 waves).
// Per step: gh = precomputed row (ghALL/gh0), GRU combine, proj via 16x16x32
// bf16x3 MFMA, logits, argmax, state update, output write.
// ---------------------------------------------------------------------------
__global__ __launch_bounds__(1024) void scan_k(
    const float* __restrict__ gi,     // [B*NST*A, GS]
    const float* __restrict__ ghALL,  // [B*NST*A, GS]
    const float* __restrict__ gh0,    // [GS]
    const float* __restrict__ inp_s,  // [B*NST*A, D]
    const us* __restrict__ w1h, const us* __restrict__ w1l,  // proj_w1 [D,D]
    const float* __restrict__ b1, const float* __restrict__ w2,
    const float* __restrict__ b2v, const float* __restrict__ s0,
    float* __restrict__ out) {
  constexpr int HS = Dd + 4;  // padded
  __shared__ float st[Dd];
  __shared__ float ghs[GSn];
  __shared__ float hs[An * HS];
  __shared__ float slog[An];
  __shared__ int samax, sprev;
  const int b = blockIdx.x, tid = threadIdx.x;
  const int wave = tid >> 6, lane = tid & 63;
  const int l15 = lane & 15, quad = lane >> 4;
  for (int j = tid; j < Dd; j += 1024) st[j] = s0[j];
  __syncthreads();
  for (int s = 0; s < NST; s++) {
    const float* gsrc = (s == 0) ? gh0 : (ghALL + (size_t)sprev * GSn);
    for (int j = tid; j < GSn; j += 1024) ghs[j] = gsrc[j];
    if (tid < An) slog[tid] = b2v[0];
    __syncthreads();
    // GRU combine -> hs
    size_t gbase = ((size_t)(b * NST + s) * An) * GSn;
    for (int idx = tid; idx < An * Dd; idx += 1024) {
      int a = idx / Dd, j = idx - a * Dd;
      const float* gp = gi + gbase + (size_t)a * GSn;
      float ir = gp[j], iz = gp[Dd + j], inn = gp[2 * Dd + j];
      float hr = ghs[j], hz = ghs[Dd + j], hn = ghs[2 * Dd + j];
      float rg = 1.f / (1.f + expf(-(ir + hr)));
      float zg = 1.f / (1.f + expf(-(iz + hz)));
      float ng = tanhf(inn + rg * hn);
      hs[a * HS + j] = (1.f - zg) * ng + zg * st[j];
    }
    __syncthreads();
    // proj via MFMA: wave -> 3 n-tiles of 16
    {
      floatx4 ahh[3], ahl[3], alh[3];
#pragma unroll
      for (int t = 0; t < 3; t++)
#pragma unroll
        for (int r = 0; r < 4; r++) { ahh[t][r] = 0.f; ahl[t][r] = 0.f; alh[t][r] = 0.f; }
      for (int k0 = 0; k0 < Dd; k0 += 32) {
        int kb = k0 + quad * 8;
        float4 v0 = *(const float4*)&hs[l15 * HS + kb];
        float4 v1 = *(const float4*)&hs[l15 * HS + kb + 4];
        float vv[8] = {v0.x, v0.y, v0.z, v0.w, v1.x, v1.y, v1.z, v1.w};
        union { us u[8]; short8 v; } fah, fal;
#pragma unroll
        for (int i = 0; i < 8; i++) {
          us hb = f2bf(vv[i]);
          fah.u[i] = hb;
          fal.u[i] = f2bf(vv[i] - bf2f(hb));
        }
#pragma unroll
        for (int t = 0; t < 3; t++) {
          int n = (wave * 3 + t) * 16 + l15;
          union { uint4 q; short8 v; } fbh, fbl;
          fbh.q = *(const uint4*)(w1h + (size_t)n * Dd + kb);
          fbl.q = *(const uint4*)(w1l + (size_t)n * Dd + kb);
          ahh[t] = __builtin_amdgcn_mfma_f32_16x16x32_bf16(fah.v, fbh.v, ahh[t], 0, 0, 0);
          ahl[t] = __builtin_amdgcn_mfma_f32_16x16x32_bf16(fah.v, fbl.v, ahl[t], 0, 0, 0);
          alh[t] = __builtin_amdgcn_mfma_f32_16x16x32_bf16(fal.v, fbh.v, alh[t], 0, 0, 0);
        }
      }
#pragma unroll
      for (int t = 0; t < 3; t++) {
        int n = (wave * 3 + t) * 16 + l15;
        float bn = b1[n], wn = w2[n];
#pragma unroll
        for (int r = 0; r < 4; r++) {
          int m = quad * 4 + r;
          float v = ahh[t][r] + ahl[t][r] + alh[t][r] + bn;
          v = fmaxf(v, 0.f) * wn;
          v += __shfl_xor(v, 1);
          v += __shfl_xor(v, 2);
          v += __shfl_xor(v, 4);
          v += __shfl_xor(v, 8);
          if (l15 == 0) atomicAdd(&slog[m], v);
        }
      }
    }
    __syncthreads();
    if (tid == 0) {
      float best = slog[0];
      int bi = 0;
      for (int a = 1; a < An; a++)
        if (slog[a] > best) { best = slog[a]; bi = a; }
      samax = bi;
      sprev = (b * NST + s) * An + bi;
    }
    __syncthreads();
    if (tid < An) out[(size_t)(b * NST + s) * An + tid] = slog[tid];
    const float* srow = inp_s + (size_t)sprev * Dd;
    for (int j = tid; j < Dd; j += 1024) st[j] = srow[j];
    __syncthreads();
  }
}

// ---------------------------------------------------------------------------
static inline void mm(const us* Ah, const us* Al, int lda, const us* Bh, const us* Bl,
                      const float* bias, float* Cf, int ldc, us* Ch, us* Cl, int ldch,
                      int M, int N, int K, int relu, hipStream_t st) {
  dim3 g(N / 64, M / 64);
  mfma_nt<<<g, 256, 0, st>>>(Ah, Al, lda, Bh, Bl, bias, Cf, ldc, Ch, Cl, ldch, K, relu);
}
static inline void sgemm(const float* A, const float* W, const float* bias, float* C,
                         int M, int N, int K, int lda, int ldc, int relu, hipStream_t st) {
  dim3 g((N + 63) / 64, (M + 63) / 64);
  gemm_s<<<g, 256, 0, st>>>(A, W, bias, C, M, N, K, lda, ldc, relu);
}
static inline void split(const float* x, us* h, us* l, int n, hipStream_t st) {
  int blocks = (n + 255) / 256;
  if (blocks > 4096) blocks = 4096;
  split_k<<<blocks, 256, 0, st>>>(x, h, l, n);
}

extern "C" void kernel_launch(void* const* d_in, const int* in_sizes, int n_in,
                              void* d_out, int out_size, void* d_ws, size_t ws_size,
                              hipStream_t stream) {
  const float* video     = (const float*)d_in[0];
  const float* script    = (const float*)d_in[1];
  const float* question  = (const float*)d_in[2];
  const float* a_texts   = (const float*)d_in[3];
  const float* a_buttons = (const float*)d_in[4];
  const float* v_w1 = (const float*)d_in[5];
  const float* v_b1 = (const float*)d_in[6];
  const float* v_w2 = (const float*)d_in[7];
  const float* v_b2 = (const float*)d_in[8];
  const float* t_w1 = (const float*)d_in[9];
  const float* t_b1 = (const float*)d_in[10];
  const float* t_w2 = (const float*)d_in[11];
  const float* t_b2 = (const float*)d_in[12];
  const float* pre_w1 = (const float*)d_in[13];
  const float* pre_b1 = (const float*)d_in[14];
  const float* pre_w2 = (const float*)d_in[15];
  const float* pre_b2 = (const float*)d_in[16];
  const float* s2v_win  = (const float*)d_in[17];
  const float* s2v_bin  = (const float*)d_in[18];
  const float* s2v_wout = (const float*)d_in[19];
  const float* s2v_bout = (const float*)d_in[20];
  const float* qa_win  = (const float*)d_in[21];
  const float* qa_bin  = (const float*)d_in[22];
  const float* qa_wout = (const float*)d_in[23];
  const float* qa_bout = (const float*)d_in[24];
  const float* gru_wih = (const float*)d_in[25];
  const float* gru_whh = (const float*)d_in[26];
  const float* gru_bih = (const float*)d_in[27];
  const float* gru_bhh = (const float*)d_in[28];
  const float* proj_w1 = (const float*)d_in[29];
  const float* proj_b1 = (const float*)d_in[30];
  const float* proj_w2 = (const float*)d_in[31];
  const float* proj_b2 = (const float*)d_in[32];
  const float* state0  = (const float*)d_in[33];
  (void)in_sizes; (void)n_in; (void)out_size; (void)ws_size;

  constexpr int W589  = 768 * 768;
  constexpr int W1769 = 2304 * 768;
  constexpr int W9437 = 3072 * 3072;
  constexpr int W2359 = 768 * 3072;
  constexpr int SMe   = 1024 * 768;
  constexpr int BIGe  = 4096 * 768;

  char* base = (char*)d_ws;
  char* RW1 = base;                   // 9,437,184
  char* RW2 = RW1 + 9437184;          // 9,437,184
  char* R1  = RW2 + 9437184;          // 28,311,552
  char* R2  = R1 + 28311552;          // 12,582,912
  char* X   = R2 + 12582912;          // 25,165,824
  char* P   = X + 25165824;           // ~19 MB

  // RW1: phase-A weights
  us* vw1h = (us*)RW1;        us* vw1l = vw1h + W589;
  us* vw2h = vw1l + W589;     us* vw2l = vw2h + W589;
  us* tw1h = vw2l + W589;     us* tw1l = tw1h + W589;
  us* tw2h = tw1l + W589;     us* tw2l = tw2h + W589;
  // RW2: sequential reuse
  us* s2vwh = (us*)RW2;       us* s2vwl = s2vwh + W1769;
  us* s2voh = s2vwl + W1769;  us* s2vol = s2voh + W589;
  us* qawh  = (us*)RW2;       us* qawl  = qawh + W1769;
  us* qaoh  = qawl + W1769;   us* qaol  = qaoh + W589;
  us* pw2h  = (us*)RW2;       us* pw2l  = pw2h + W2359;
  // R1 timeline
  us* vidh = (us*)R1;         us* vidl = vidh + BIGe;
  us* hidh = vidl + BIGe;     us* hidl = hidh + BIGe;
  us* scrh = (us*)R1;         us* scrl = scrh + SMe;
  float* kvproj = (float*)R1;                       // [4096 x 1536]
  float* qproj  = kvproj + (size_t)4096 * 1536;     // [1024 x 768]
  float* kv2 = (float*)R1;                          // [1024 x 1536]
  float* qp2 = (float*)(R1 + 6291456);
  float* S2  = (float*)(R1 + 9437184);              // 6,291,456 B
  us* abhh = (us*)(R1 + 15728640); us* abhl = abhh + SMe;
  us* pw1h = (us*)R1;         us* pw1l = pw1h + W9437;   // spans into R2
  us* gwihh = (us*)R1;        us* gwihl = gwihh + W1769;
  us* pjw1h = (us*)(R1 + 7077888);  us* pjw1l = pjw1h + W589;
  us* gwhhh = (us*)(R1 + 9437184);  us* gwhhl = gwhhh + W1769;
  // R2
  us* vh = (us*)R2;           us* vl = vh + BIGe;
  float* attnout = (float*)R2;
  us* aoh = (us*)(R2 + 3145728); us* aol = aoh + SMe;
  // X
  float* S1 = (float*)X;
  us* cath = (us*)X;          us* catl = cath + (size_t)1024 * DPn;
  us* prehh = (us*)(X + 12582912); us* prehl = prehh + (size_t)1024 * DPn;
  float* gi    = (float*)X;                  // 9,437,184 B
  float* ghALL = (float*)(X + 9437184);      // 9,437,184 B
  // P
  us* abinh = (us*)P;         us* abinl = abinh + SMe;
  us* sch   = (us*)(P + 3145728); us* scl = sch + SMe;
  float* at_f   = (float*)(P + 6291456);
  float* vatt   = (float*)(P + 9437184);
  float* inps_f = (float*)(P + 12582912);
  us* inpsh = (us*)(P + 15728640); us* inpsl = inpsh + SMe;
  float* qf   = (float*)(P + 18874368);
  float* qhid = (float*)(P + 18898944);
  float* gh0  = (float*)(P + 18923520);

  // ---- phase A ----
  split4_k<<<dim3(2048, 4), 256, 0, stream>>>(v_w1, vw1h, vw1l, W589,
                                              v_w2, vw2h, vw2l, W589,
                                              t_w1, tw1h, tw1l, W589,
                                              t_w2, tw2h, tw2l, W589);
  split(video, vidh, vidl, BIGe, stream);
  mm(vidh, vidl, Dd, vw1h, vw1l, v_b1, nullptr, 0, hidh, hidl, Dd, 4096, Dd, Dd, 1, stream);
  mm(hidh, hidl, Dd, vw2h, vw2l, v_b2, nullptr, 0, vh, vl, Dd, 4096, Dd, Dd, 0, stream);
  split(script, scrh, scrl, SMe, stream);
  mm(scrh, scrl, Dd, tw1h, tw1l, t_b1, nullptr, 0, hidh, hidl, Dd, 1024, Dd, Dd, 1, stream);
  mm(hidh, hidl, Dd, tw2h, tw2l, t_b2, nullptr, 0, sch, scl, Dd, 1024, Dd, Dd, 0, stream);
  sgemm(question, t_w1, t_b1, qhid, Bn, Dd, Dd, Dd, Dd, 1, stream);
  sgemm(qhid, t_w2, t_b2, qf, Bn, Dd, Dd, Dd, Dd, 0, stream);
  split(a_texts, scrh, scrl, SMe, stream);
  mm(scrh, scrl, Dd, tw1h, tw1l, t_b1, nullptr, 0, hidh, hidl, Dd, 1024, Dd, Dd, 1, stream);
  mm(hidh, hidl, Dd, tw2h, tw2l, t_b2, at_f, Dd, nullptr, nullptr, 0, 1024, Dd, Dd, 0, stream);
  split(a_buttons, abinh, abinl, SMe, stream);

  // ---- s2v attention (K/V merged: N=1536) ----
  split4_k<<<dim3(2048, 4), 256, 0, stream>>>(s2v_win, s2vwh, s2vwl, W1769,
                                              s2v_wout, s2voh, s2vol, W589,
                                              nullptr, nullptr, nullptr, 0,
                                              nullptr, nullptr, nullptr, 0);
  mm(vh, vl, Dd, s2vwh + (size_t)Dd * Dd, s2vwl + (size_t)Dd * Dd, s2v_bin + Dd,
     kvproj, 1536, nullptr, nullptr, 0, 4096, 1536, Dd, 0, stream);
  mm(sch, scl, Dd, s2vwh, s2vwl, s2v_bin, qproj, Dd, nullptr, nullptr, 0, 1024, Dd, Dd, 0, stream);
  att_qk<<<dim3(Bn * NH, TSn / 32, TVn / 64), 256, 0, stream>>>(qproj, kvproj, S1,
                                                                TSn, TVn, 1, 1536, 0.125f);
  softmax_rows<<<Bn * NH * TSn, 256, 0, stream>>>(S1, TVn);
  att_pv<<<dim3(Bn * NH, TSn / 32), 256, 0, stream>>>(S1, kvproj + Dd, attnout,
                                                      TSn, TVn, 1, 1536);
  split(attnout, aoh, aol, SMe, stream);
  mm(aoh, aol, Dd, s2voh, s2vol, s2v_bout, vatt, Dd, nullptr, nullptr, 0, 1024, Dd, Dd, 0, stream);

  // ---- phase B: ab MLP, qa attention (K/V merged) ----
  mm(abinh, abinl, Dd, vw1h, vw1l, v_b1, nullptr, 0, abhh, abhl, Dd, 1024, Dd, Dd, 1, stream);
  mm(abhh, abhl, Dd, vw2h, vw2l, v_b2, nullptr, 0, cath + 3 * Dd, catl + 3 * Dd, DPn,
     1024, Dd, Dd, 0, stream);
  qa_add<<<(1024 * Dd + 255) / 256, 256, 0, stream>>>(qf, at_f, cath, catl);
  split4_k<<<dim3(2048, 4), 256, 0, stream>>>(qa_win, qawh, qawl, W1769,
                                              qa_wout, qaoh, qaol, W589,
                                              nullptr, nullptr, nullptr, 0,
                                              nullptr, nullptr, nullptr, 0);
  mm(sch, scl, Dd, qawh + (size_t)Dd * Dd, qawl + (size_t)Dd * Dd, qa_bin + Dd,
     kv2, 1536, nullptr, nullptr, 0, 1024, 1536, Dd, 0, stream);
  mm(cath + 2 * Dd, catl + 2 * Dd, DPn, qawh, qawl, qa_bin, qp2, Dd, nullptr, nullptr, 0,
     1024, Dd, Dd, 0, stream);
  att_qk<<<dim3(Bn * NST * NH, 1, TSn / 64), 256, 0, stream>>>(qp2, kv2, S2,
                                                               An, TSn, NST, 1536, 0.125f);
  softmax_rows<<<Bn * NST * NH * An, 256, 0, stream>>>(S2, TSn);
  att_pv<<<dim3(Bn * NST * NH, 1), 256, 0, stream>>>(S2, kv2 + Dd, attnout,
                                                     An, TSn, NST, 1536);
  split(attnout, aoh, aol, SMe, stream);
  mm(aoh, aol, Dd, qaoh, qaol, qa_bout, nullptr, 0, cath + Dd, catl + Dd, DPn,
     1024, Dd, Dd, 0, stream);
  qv2_k<<<1024, 256, 0, stream>>>(S2, vatt, cath, catl);

  // ---- pre-MLP + GRU gate precompute ----
  split(pre_w1, pw1h, pw1l, W9437, stream);
  mm(cath, catl, DPn, pw1h, pw1l, pre_b1, nullptr, 0, prehh, prehl, DPn,
     1024, DPn, DPn, 1, stream);
  split4_k<<<dim3(2048, 4), 256, 0, stream>>>(pre_w2, pw2h, pw2l, W2359,
                                              gru_wih, gwihh, gwihl, W1769,
                                              gru_whh, gwhhh, gwhhl, W1769,
                                              proj_w1, pjw1h, pjw1l, W589);
  mm(prehh, prehl, DPn, pw2h, pw2l, pre_b2, inps_f, Dd, inpsh, inpsl, Dd,
     1024, Dd, DPn, 0, stream);
  mm(inpsh, inpsl, Dd, gwihh, gwihl, gru_bih, gi, GSn, nullptr, nullptr, 0,
     1024, GSn, Dd, 0, stream);
  mm(inpsh, inpsl, Dd, gwhhh, gwhhl, gru_bhh, ghALL, GSn, nullptr, nullptr, 0,
     1024, GSn, Dd, 0, stream);
  sgemm(state0, gru_whh, gru_bhh, gh0, 1, GSn, Dd, Dd, GSn, 0, stream);

  // ---- fused scan ----
  scan_k<<<Bn, 1024, 0, stream>>>(gi, ghALL, gh0, inps_f, pjw1h, pjw1l,
                                  proj_b1, proj_w2, proj_b2, state0, (float*)d_out);
}

// Round 6
// 1340.111 us; speedup vs baseline: 2.9618x; 1.3346x over previous
//
#include <hip/hip_runtime.h>
#include <hip/hip_bf16.h>
#include <math.h>

constexpr int Dd  = 768;
constexpr int NH  = 12;
constexpr int DHd = 64;
constexpr int Bn  = 8;
constexpr int TVn = 512;
constexpr int TSn = 128;
constexpr int NST = 8;
constexpr int An  = 16;
constexpr int DPn = 3072;
constexpr int GSn = 2304;
constexpr int Mtot = 14464;   // 128 (s=0) + 8*7*16*16 candidate rows; 226*64

typedef unsigned short us;
using short8   = __attribute__((ext_vector_type(8))) short;
using floatx16 = __attribute__((ext_vector_type(16))) float;

__device__ inline us f2bf(float x) {
  union { float f; unsigned u; } a; a.f = x;
  return (us)((a.u + 0x7fffu + ((a.u >> 16) & 1u)) >> 16);
}
__device__ inline float bf2f(us h) {
  union { unsigned u; float f; } a; a.u = ((unsigned)h) << 16;
  return a.f;
}

// ---------------------------------------------------------------------------
// splits
// ---------------------------------------------------------------------------
__global__ void split_k(const float* __restrict__ x, us* __restrict__ h,
                        us* __restrict__ l, int n) {
  for (int i = blockIdx.x * 256 + threadIdx.x; i < n; i += gridDim.x * 256) {
    float v = x[i];
    us hb = f2bf(v);
    h[i] = hb;
    l[i] = f2bf(v - bf2f(hb));
  }
}

__global__ void split4_k(const float* s0, us* h0, us* l0, int n0,
                         const float* s1, us* h1, us* l1, int n1,
                         const float* s2, us* h2, us* l2, int n2,
                         const float* s3, us* h3, us* l3, int n3) {
  const float* s; us* h; us* l; int n;
  switch (blockIdx.y) {
    case 0: s = s0; h = h0; l = l0; n = n0; break;
    case 1: s = s1; h = h1; l = l1; n = n1; break;
    case 2: s = s2; h = h2; l = l2; n = n2; break;
    default: s = s3; h = h3; l = l3; n = n3; break;
  }
  for (int i = blockIdx.x * 256 + threadIdx.x; i < n; i += gridDim.x * 256) {
    float v = s[i];
    us hb = f2bf(v);
    h[i] = hb;
    l[i] = f2bf(v - bf2f(hb));
  }
}

// ---------------------------------------------------------------------------
// bf16x3 MFMA NT GEMM, double-buffered LDS, one barrier per K-iter.
// ---------------------------------------------------------------------------
__device__ inline short8 lds8(const us* p) {
  const uint2* q = (const uint2*)p;
  uint2 a = q[0], b = q[1];
  union { unsigned u[4]; short8 v; } t;
  t.u[0] = a.x; t.u[1] = a.y; t.u[2] = b.x; t.u[3] = b.y;
  return t.v;
}

__global__ __launch_bounds__(256) void mfma_nt(
    const us* __restrict__ Ah, const us* __restrict__ Al, int lda,
    const us* __restrict__ Bh, const us* __restrict__ Bl,
    const float* __restrict__ bias,
    float* __restrict__ Cf, int ldc,
    us* __restrict__ Ch, us* __restrict__ Cl, int ldch,
    int K, int relu) {
  __shared__ us Ash[2][64][36], Asl[2][64][36], Bsh[2][64][36], Bsl[2][64][36];
  const int tid = threadIdx.x;
  const int bm = blockIdx.y * 64, bn = blockIdx.x * 64;
  const int wave = tid >> 6, lane = tid & 63;
  const int mh = (wave & 1) * 32, nh = (wave >> 1) * 32;
  const int l31 = lane & 31, hi5 = lane >> 5;
  const int srow = tid >> 2, skc = (tid & 3) * 8;
  const us* pAh = Ah + (size_t)(bm + srow) * lda + skc;
  const us* pAl = Al + (size_t)(bm + srow) * lda + skc;
  const us* pBh = Bh + (size_t)(bn + srow) * K + skc;
  const us* pBl = Bl + (size_t)(bn + srow) * K + skc;

  floatx16 acc_hh, acc_hl, acc_lh;
#pragma unroll
  for (int i = 0; i < 16; i++) { acc_hh[i] = 0.f; acc_hl[i] = 0.f; acc_lh[i] = 0.f; }

  uint4 a_h = *(const uint4*)pAh;
  uint4 a_l = *(const uint4*)pAl;
  uint4 b_h = *(const uint4*)pBh;
  uint4 b_l = *(const uint4*)pBl;
  const int iters = K >> 5;
  int p = 0;
  for (int it = 0; it < iters; ++it) {
    *(uint2*)&Ash[p][srow][skc]     = make_uint2(a_h.x, a_h.y);
    *(uint2*)&Ash[p][srow][skc + 4] = make_uint2(a_h.z, a_h.w);
    *(uint2*)&Asl[p][srow][skc]     = make_uint2(a_l.x, a_l.y);
    *(uint2*)&Asl[p][srow][skc + 4] = make_uint2(a_l.z, a_l.w);
    *(uint2*)&Bsh[p][srow][skc]     = make_uint2(b_h.x, b_h.y);
    *(uint2*)&Bsh[p][srow][skc + 4] = make_uint2(b_h.z, b_h.w);
    *(uint2*)&Bsl[p][srow][skc]     = make_uint2(b_l.x, b_l.y);
    *(uint2*)&Bsl[p][srow][skc + 4] = make_uint2(b_l.z, b_l.w);
    __syncthreads();
    int knext = (it + 1 < iters) ? (it + 1) * 32 : 0;
    a_h = *(const uint4*)(pAh + knext);
    a_l = *(const uint4*)(pAl + knext);
    b_h = *(const uint4*)(pBh + knext);
    b_l = *(const uint4*)(pBl + knext);
#pragma unroll
    for (int ks = 0; ks < 32; ks += 16) {
      short8 fa_h = lds8(&Ash[p][mh + l31][ks + hi5 * 8]);
      short8 fa_l = lds8(&Asl[p][mh + l31][ks + hi5 * 8]);
      short8 fb_h = lds8(&Bsh[p][nh + l31][ks + hi5 * 8]);
      short8 fb_l = lds8(&Bsl[p][nh + l31][ks + hi5 * 8]);
      acc_hh = __builtin_amdgcn_mfma_f32_32x32x16_bf16(fa_h, fb_h, acc_hh, 0, 0, 0);
      acc_hl = __builtin_amdgcn_mfma_f32_32x32x16_bf16(fa_h, fb_l, acc_hl, 0, 0, 0);
      acc_lh = __builtin_amdgcn_mfma_f32_32x32x16_bf16(fa_l, fb_h, acc_lh, 0, 0, 0);
    }
    p ^= 1;
  }
#pragma unroll
  for (int r = 0; r < 16; r++) {
    int m = bm + mh + (r & 3) + 8 * (r >> 2) + 4 * hi5;
    int n = bn + nh + l31;
    float v = acc_hh[r] + acc_hl[r] + acc_lh[r] + bias[n];
    if (relu) v = fmaxf(v, 0.f);
    if (Cf) Cf[(size_t)m * ldc + n] = v;
    if (Ch) {
      us hb = f2bf(v);
      Ch[(size_t)m * ldch + n] = hb;
      Cl[(size_t)m * ldch + n] = f2bf(v - bf2f(hb));
    }
  }
}

// ---------------------------------------------------------------------------
// logit GEMM: A = H f32 [Mtot x 768] (split in-kernel), B = proj_w1 split.
// Epilogue: relu(acc + b1[n]) * w2[n], reduce over n-tile, write partials
// Lpart[ntile][m]. Grid: (12 n-tiles, 226 m-tiles).
// ---------------------------------------------------------------------------
__global__ __launch_bounds__(256) void mfma_logit(
    const float* __restrict__ H,
    const us* __restrict__ Bh, const us* __restrict__ Bl,
    const float* __restrict__ b1, const float* __restrict__ w2,
    float* __restrict__ Lpart) {
  __shared__ us Ash[2][64][36], Asl[2][64][36], Bsh[2][64][36], Bsl[2][64][36];
  __shared__ float lpart[64];
  const int tid = threadIdx.x;
  const int bm = blockIdx.y * 64, bn = blockIdx.x * 64;
  const int wave = tid >> 6, lane = tid & 63;
  const int mh = (wave & 1) * 32, nh = (wave >> 1) * 32;
  const int l31 = lane & 31, hi5 = lane >> 5;
  const int srow = tid >> 2, skc = (tid & 3) * 8;
  const int K = Dd;
  const float* pA = H + (size_t)(bm + srow) * K + skc;
  const us* pBh = Bh + (size_t)(bn + srow) * K + skc;
  const us* pBl = Bl + (size_t)(bn + srow) * K + skc;

  floatx16 acc_hh, acc_hl, acc_lh;
#pragma unroll
  for (int i = 0; i < 16; i++) { acc_hh[i] = 0.f; acc_hl[i] = 0.f; acc_lh[i] = 0.f; }
  if (tid < 64) lpart[tid] = 0.f;

  float4 af0 = *(const float4*)pA;
  float4 af1 = *(const float4*)(pA + 4);
  uint4 b_h = *(const uint4*)pBh;
  uint4 b_l = *(const uint4*)pBl;
  const int iters = K >> 5;
  int p = 0;
  for (int it = 0; it < iters; ++it) {
    {
      float av[8] = {af0.x, af0.y, af0.z, af0.w, af1.x, af1.y, af1.z, af1.w};
      us ah[8], al[8];
#pragma unroll
      for (int i = 0; i < 8; i++) {
        ah[i] = f2bf(av[i]);
        al[i] = f2bf(av[i] - bf2f(ah[i]));
      }
      *(uint2*)&Ash[p][srow][skc] =
          make_uint2(ah[0] | ((unsigned)ah[1] << 16), ah[2] | ((unsigned)ah[3] << 16));
      *(uint2*)&Ash[p][srow][skc + 4] =
          make_uint2(ah[4] | ((unsigned)ah[5] << 16), ah[6] | ((unsigned)ah[7] << 16));
      *(uint2*)&Asl[p][srow][skc] =
          make_uint2(al[0] | ((unsigned)al[1] << 16), al[2] | ((unsigned)al[3] << 16));
      *(uint2*)&Asl[p][srow][skc + 4] =
          make_uint2(al[4] | ((unsigned)al[5] << 16), al[6] | ((unsigned)al[7] << 16));
    }
    *(uint2*)&Bsh[p][srow][skc]     = make_uint2(b_h.x, b_h.y);
    *(uint2*)&Bsh[p][srow][skc + 4] = make_uint2(b_h.z, b_h.w);
    *(uint2*)&Bsl[p][srow][skc]     = make_uint2(b_l.x, b_l.y);
    *(uint2*)&Bsl[p][srow][skc + 4] = make_uint2(b_l.z, b_l.w);
    __syncthreads();
    int knext = (it + 1 < iters) ? (it + 1) * 32 : 0;
    af0 = *(const float4*)(pA + knext);
    af1 = *(const float4*)(pA + knext + 4);
    b_h = *(const uint4*)(pBh + knext);
    b_l = *(const uint4*)(pBl + knext);
#pragma unroll
    for (int ks = 0; ks < 32; ks += 16) {
      short8 fa_h = lds8(&Ash[p][mh + l31][ks + hi5 * 8]);
      short8 fa_l = lds8(&Asl[p][mh + l31][ks + hi5 * 8]);
      short8 fb_h = lds8(&Bsh[p][nh + l31][ks + hi5 * 8]);
      short8 fb_l = lds8(&Bsl[p][nh + l31][ks + hi5 * 8]);
      acc_hh = __builtin_amdgcn_mfma_f32_32x32x16_bf16(fa_h, fb_h, acc_hh, 0, 0, 0);
      acc_hl = __builtin_amdgcn_mfma_f32_32x32x16_bf16(fa_h, fb_l, acc_hl, 0, 0, 0);
      acc_lh = __builtin_amdgcn_mfma_f32_32x32x16_bf16(fa_l, fb_h, acc_lh, 0, 0, 0);
    }
    p ^= 1;
  }
  int n = bn + nh + l31;
  float bn1 = b1[n], wn = w2[n];
#pragma unroll
  for (int r = 0; r < 16; r++) {
    int mloc = mh + (r & 3) + 8 * (r >> 2) + 4 * hi5;
    float v = acc_hh[r] + acc_hl[r] + acc_lh[r] + bn1;
    v = fmaxf(v, 0.f) * wn;
    v += __shfl_xor(v, 1);
    v += __shfl_xor(v, 2);
    v += __shfl_xor(v, 4);
    v += __shfl_xor(v, 8);
    v += __shfl_xor(v, 16);
    if (l31 == 0) atomicAdd(&lpart[mloc], v);
  }
  __syncthreads();
  if (tid < 64) Lpart[(size_t)blockIdx.x * Mtot + bm + tid] = lpart[tid];
}

// ---------------------------------------------------------------------------
// scalar f32 NT GEMM (tiny M: question, gh0)
// ---------------------------------------------------------------------------
__global__ __launch_bounds__(256) void gemm_s(const float* __restrict__ A,
                                              const float* __restrict__ Bw,
                                              const float* __restrict__ bias,
                                              float* __restrict__ C,
                                              int M, int N, int K,
                                              int lda, int ldc, int relu) {
  __shared__ float As[16][65];
  __shared__ float Bs[16][65];
  int bm = blockIdx.y * 64, bn = blockIdx.x * 64;
  int tid = threadIdx.x;
  int tx = tid & 15, ty = tid >> 4;
  float acc[4][4] = {};
  for (int k0 = 0; k0 < K; k0 += 16) {
#pragma unroll
    for (int i = 0; i < 4; i++) {
      int l = tid * 4 + i;
      int row = l >> 4, kk = l & 15;
      float v = 0.f;
      if (bm + row < M) v = A[(size_t)(bm + row) * lda + k0 + kk];
      As[kk][row] = v;
    }
#pragma unroll
    for (int i = 0; i < 4; i++) {
      int l = tid * 4 + i;
      int row = l >> 4, kk = l & 15;
      float v = 0.f;
      if (bn + row < N) v = Bw[(size_t)(bn + row) * K + k0 + kk];
      Bs[kk][row] = v;
    }
    __syncthreads();
#pragma unroll
    for (int kk = 0; kk < 16; kk++) {
      float a4[4], b4[4];
#pragma unroll
      for (int i = 0; i < 4; i++) a4[i] = As[kk][ty * 4 + i];
#pragma unroll
      for (int j = 0; j < 4; j++) b4[j] = Bs[kk][tx * 4 + j];
#pragma unroll
      for (int i = 0; i < 4; i++)
#pragma unroll
        for (int j = 0; j < 4; j++) acc[i][j] += a4[i] * b4[j];
    }
    __syncthreads();
  }
#pragma unroll
  for (int i = 0; i < 4; i++) {
    int m = bm + ty * 4 + i;
    if (m >= M) continue;
#pragma unroll
    for (int j = 0; j < 4; j++) {
      int n = bn + tx * 4 + j;
      if (n >= N) continue;
      float v = acc[i][j] + bias[n];
      if (relu) v = fmaxf(v, 0.f);
      C[(size_t)m * ldc + n] = v;
    }
  }
}

// ---------------------------------------------------------------------------
// attention (f32)
// ---------------------------------------------------------------------------
__global__ __launch_bounds__(256) void att_qk(const float* __restrict__ qp,
                                              const float* __restrict__ kp,
                                              float* __restrict__ Sout,
                                              int Tq, int Tk, int kdiv, int ldk,
                                              float scale) {
  int g = blockIdx.x;
  int h = g % NH;
  int qrow0 = (g / NH) * Tq;
  int krow0 = (g / (NH * kdiv)) * Tk;
  int q0 = blockIdx.y * 32;
  int k0 = blockIdx.z * 64;
  __shared__ float Qs[32][DHd + 1];
  __shared__ float Ks[64][DHd + 1];
  int tid = threadIdx.x;
  {
    int row = tid >> 3, db = (tid & 7) * 8;
    int qr = q0 + row;
#pragma unroll
    for (int i = 0; i < 8; i++) {
      float v = 0.f;
      if (qr < Tq) v = qp[(size_t)(qrow0 + qr) * Dd + h * DHd + db + i];
      Qs[row][db + i] = v;
    }
  }
#pragma unroll
  for (int half = 0; half < 2; half++) {
    int row = (tid >> 3) + half * 32, db = (tid & 7) * 8;
    int kr = k0 + row;
#pragma unroll
    for (int i = 0; i < 8; i++) {
      float v = 0.f;
      if (kr < Tk) v = kp[(size_t)(krow0 + kr) * ldk + h * DHd + db + i];
      Ks[row][db + i] = v;
    }
  }
  __syncthreads();
  int q = tid >> 3, kg = tid & 7;
  float acc[8] = {};
  for (int d = 0; d < DHd; d++) {
    float qv = Qs[q][d];
#pragma unroll
    for (int j = 0; j < 8; j++) acc[j] += qv * Ks[kg * 8 + j][d];
  }
  if (q0 + q < Tq) {
    size_t base = ((size_t)g * Tq + q0 + q) * Tk + k0 + kg * 8;
#pragma unroll
    for (int j = 0; j < 8; j++) Sout[base + j] = acc[j] * scale;
  }
}

__global__ __launch_bounds__(256) void att_pv(const float* __restrict__ P,
                                              const float* __restrict__ vp,
                                              float* __restrict__ Out,
                                              int Tq, int Tk, int kdiv, int ldv) {
  int g = blockIdx.x;
  int h = g % NH;
  int qrow0 = (g / NH) * Tq;
  int krow0 = (g / (NH * kdiv)) * Tk;
  int q0 = blockIdx.y * 32;
  __shared__ float Ps[32][65];
  __shared__ float Vs[64][DHd + 1];
  int tid = threadIdx.x;
  int q = tid >> 3, dg = tid & 7;
  float acc[8] = {};
  for (int k0 = 0; k0 < Tk; k0 += 64) {
    {
      int row = tid >> 3, cb = (tid & 7) * 8;
      int qr = q0 + row;
#pragma unroll
      for (int i = 0; i < 8; i++) {
        float v = 0.f;
        if (qr < Tq) v = P[((size_t)g * Tq + qr) * Tk + k0 + cb + i];
        Ps[row][cb + i] = v;
      }
    }
#pragma unroll
    for (int half = 0; half < 2; half++) {
      int row = (tid >> 3) + half * 32, db = (tid & 7) * 8;
#pragma unroll
      for (int i = 0; i < 8; i++)
        Vs[row][db + i] = vp[(size_t)(krow0 + k0 + row) * ldv + h * DHd + db + i];
    }
    __syncthreads();
    for (int kk = 0; kk < 64; kk++) {
      float p = Ps[q][kk];
#pragma unroll
      for (int j = 0; j < 8; j++) acc[j] += p * Vs[kk][dg * 8 + j];
    }
    __syncthreads();
  }
  if (q0 + q < Tq) {
    size_t base = (size_t)(qrow0 + q0 + q) * Dd + h * DHd + dg * 8;
#pragma unroll
    for (int j = 0; j < 8; j++) Out[base + j] = acc[j];
  }
}

__global__ __launch_bounds__(256) void softmax_rows(float* __restrict__ X, int len) {
  int row = blockIdx.x;
  float* p = X + (size_t)row * len;
  int tid = threadIdx.x;
  __shared__ float red[4];
  __shared__ float red2[4];
  float lmax = -1e30f;
  for (int j = tid; j < len; j += 256) lmax = fmaxf(lmax, p[j]);
  for (int off = 32; off; off >>= 1) lmax = fmaxf(lmax, __shfl_down(lmax, off));
  if ((tid & 63) == 0) red[tid >> 6] = lmax;
  __syncthreads();
  if (tid == 0) red[0] = fmaxf(fmaxf(red[0], red[1]), fmaxf(red[2], red[3]));
  __syncthreads();
  float m = red[0];
  float lsum = 0.f;
  for (int j = tid; j < len; j += 256) {
    float e = expf(p[j] - m);
    p[j] = e;
    lsum += e;
  }
  for (int off = 32; off; off >>= 1) lsum += __shfl_down(lsum, off);
  if ((tid & 63) == 0) red2[tid >> 6] = lsum;
  __syncthreads();
  if (tid == 0) red2[0] = red2[0] + red2[1] + red2[2] + red2[3];
  __syncthreads();
  float inv = 1.f / red2[0];
  for (int j = tid; j < len; j += 256) p[j] *= inv;
}

// fused head-mean + qv = W @ vatt -> cat slice [0,D)
__global__ __launch_bounds__(256) void qv2_k(const float* __restrict__ S2,
                                             const float* __restrict__ vatt,
                                             us* __restrict__ ch, us* __restrict__ cl) {
  int row = blockIdx.x;
  int b = row / (NST * An);
  int bs = row / An;
  int a = row % An;
  __shared__ float wm[TSn];
  int tid = threadIdx.x;
  if (tid < TSn) {
    float acc = 0.f;
    for (int h = 0; h < NH; h++)
      acc += S2[(((size_t)bs * NH + h) * An + a) * TSn + tid];
    wm[tid] = acc * (1.f / NH);
  }
  __syncthreads();
  for (int j = tid; j < Dd; j += 256) {
    float acc = 0.f;
    for (int k = 0; k < TSn; k++)
      acc += wm[k] * vatt[((size_t)b * TSn + k) * Dd + j];
    size_t o = (size_t)row * DPn + j;
    us hb = f2bf(acc);
    ch[o] = hb;
    cl[o] = f2bf(acc - bf2f(hb));
  }
}

// qa = qf[b] + at[row] -> cat slice [2D,3D)
__global__ void qa_add(const float* __restrict__ qf, const float* __restrict__ at,
                       us* __restrict__ ch, us* __restrict__ cl) {
  int idx = blockIdx.x * 256 + threadIdx.x;
  if (idx >= Bn * NST * An * Dd) return;
  int b = idx / (NST * An * Dd);
  int row = idx / Dd;
  int j = idx % Dd;
  float v = qf[b * Dd + j] + at[idx];
  size_t o = (size_t)row * DPn + 2 * Dd + j;
  us hb = f2bf(v);
  ch[o] = hb;
  cl[o] = f2bf(v - bf2f(hb));
}

// ---------------------------------------------------------------------------
// GRU combine for ALL candidate (step, answer, state-candidate) rows.
// Row layout: [0,128): s=0 rows (b,a) with gh0/state0.
//             [128,14464): 128 + (((b*7+(s-1))*16 + a)*16 + c).
// ---------------------------------------------------------------------------
__global__ void combine_all(const float* __restrict__ gi,
                            const float* __restrict__ ghALL,
                            const float* __restrict__ gh0,
                            const float* __restrict__ inps,
                            const float* __restrict__ state0,
                            float* __restrict__ H) {
  int idx = blockIdx.x * 256 + threadIdx.x;
  if (idx >= Mtot * Dd) return;
  int row = idx / Dd, j = idx - row * Dd;
  const float* gp;
  const float* ghp;
  const float* stp;
  if (row < 128) {
    int b = row >> 4, a = row & 15;
    gp = gi + ((size_t)(b * NST) * An + a) * GSn;
    ghp = gh0;
    stp = state0;
  } else {
    int r = row - 128;
    int c = r & 15; r >>= 4;
    int a = r & 15; r >>= 4;
    int sm1 = r % 7, b = r / 7;
    size_t prev = (size_t)(b * NST + sm1) * An + c;
    gp = gi + ((size_t)(b * NST + sm1 + 1) * An + a) * GSn;
    ghp = ghALL + prev * GSn;
    stp = inps + prev * Dd;
  }
  float ir = gp[j], iz = gp[Dd + j], inn = gp[2 * Dd + j];
  float hr = ghp[j], hz = ghp[Dd + j], hn = ghp[2 * Dd + j];
  float rg = 1.f / (1.f + expf(-(ir + hr)));
  float zg = 1.f / (1.f + expf(-(iz + hz)));
  float ng = tanhf(inn + rg * hn);
  H[idx] = (1.f - zg) * ng + zg * stp[j];
}

// ---------------------------------------------------------------------------
// pick: walk the argmax chain over precomputed logit partials.
// one block (64 thr) per batch item.
// ---------------------------------------------------------------------------
__global__ __launch_bounds__(64) void pick_k(const float* __restrict__ Lpart,
                                             const float* __restrict__ b2v,
                                             float* __restrict__ out) {
  int b = blockIdx.x;
  int lane = threadIdx.x;
  int c = 0;
  float b2 = b2v[0];
  for (int s = 0; s < NST; s++) {
    int row;
    if (s == 0) row = b * 16 + (lane & 15);
    else row = 128 + (((b * 7 + (s - 1)) * 16 + (lane & 15)) * 16 + c);
    float v = 0.f;
#pragma unroll
    for (int t = 0; t < 12; t++) v += Lpart[(size_t)t * Mtot + row];
    v += b2;
    if (lane < 16) out[(size_t)(b * NST + s) * An + lane] = v;
    float bv = (lane < 16) ? v : -1e30f;
    int bi = (lane < 16) ? lane : 999;
#pragma unroll
    for (int off = 1; off < 16; off <<= 1) {
      float ov = __shfl_xor(bv, off);
      int oi = __shfl_xor(bi, off);
      if (ov > bv || (ov == bv && oi < bi)) { bv = ov; bi = oi; }
    }
    c = __shfl(bi, 0);
  }
}

// ---------------------------------------------------------------------------
static inline void mm(const us* Ah, const us* Al, int lda, const us* Bh, const us* Bl,
                      const float* bias, float* Cf, int ldc, us* Ch, us* Cl, int ldch,
                      int M, int N, int K, int relu, hipStream_t st) {
  dim3 g(N / 64, M / 64);
  mfma_nt<<<g, 256, 0, st>>>(Ah, Al, lda, Bh, Bl, bias, Cf, ldc, Ch, Cl, ldch, K, relu);
}
static inline void sgemm(const float* A, const float* W, const float* bias, float* C,
                         int M, int N, int K, int lda, int ldc, int relu, hipStream_t st) {
  dim3 g((N + 63) / 64, (M + 63) / 64);
  gemm_s<<<g, 256, 0, st>>>(A, W, bias, C, M, N, K, lda, ldc, relu);
}
static inline void split(const float* x, us* h, us* l, int n, hipStream_t st) {
  int blocks = (n + 255) / 256;
  if (blocks > 4096) blocks = 4096;
  split_k<<<blocks, 256, 0, st>>>(x, h, l, n);
}

extern "C" void kernel_launch(void* const* d_in, const int* in_sizes, int n_in,
                              void* d_out, int out_size, void* d_ws, size_t ws_size,
                              hipStream_t stream) {
  const float* video     = (const float*)d_in[0];
  const float* script    = (const float*)d_in[1];
  const float* question  = (const float*)d_in[2];
  const float* a_texts   = (const float*)d_in[3];
  const float* a_buttons = (const float*)d_in[4];
  const float* v_w1 = (const float*)d_in[5];
  const float* v_b1 = (const float*)d_in[6];
  const float* v_w2 = (const float*)d_in[7];
  const float* v_b2 = (const float*)d_in[8];
  const float* t_w1 = (const float*)d_in[9];
  const float* t_b1 = (const float*)d_in[10];
  const float* t_w2 = (const float*)d_in[11];
  const float* t_b2 = (const float*)d_in[12];
  const float* pre_w1 = (const float*)d_in[13];
  const float* pre_b1 = (const float*)d_in[14];
  const float* pre_w2 = (const float*)d_in[15];
  const float* pre_b2 = (const float*)d_in[16];
  const float* s2v_win  = (const float*)d_in[17];
  const float* s2v_bin  = (const float*)d_in[18];
  const float* s2v_wout = (const float*)d_in[19];
  const float* s2v_bout = (const float*)d_in[20];
  const float* qa_win  = (const float*)d_in[21];
  const float* qa_bin  = (const float*)d_in[22];
  const float* qa_wout = (const float*)d_in[23];
  const float* qa_bout = (const float*)d_in[24];
  const float* gru_wih = (const float*)d_in[25];
  const float* gru_whh = (const float*)d_in[26];
  const float* gru_bih = (const float*)d_in[27];
  const float* gru_bhh = (const float*)d_in[28];
  const float* proj_w1 = (const float*)d_in[29];
  const float* proj_b1 = (const float*)d_in[30];
  const float* proj_w2 = (const float*)d_in[31];
  const float* proj_b2 = (const float*)d_in[32];
  const float* state0  = (const float*)d_in[33];
  (void)in_sizes; (void)n_in; (void)out_size; (void)ws_size;

  constexpr int W589  = 768 * 768;
  constexpr int W1769 = 2304 * 768;
  constexpr int W9437 = 3072 * 3072;
  constexpr int W2359 = 768 * 3072;
  constexpr int SMe   = 1024 * 768;
  constexpr int BIGe  = 4096 * 768;

  char* base = (char*)d_ws;
  char* RW1 = base;                   // 9,437,184 : phase-A weights -> ghALL
  char* RW2 = RW1 + 9437184;          // 9,437,184 : s2v/qa/pre_w2 weights -> gi
  char* R1  = RW2 + 9437184;          // 28,311,552
  char* R2  = R1 + 28311552;          // 12,582,912
  char* X   = R2 + 12582912;          // 25,165,824
  char* P   = X + 25165824;           // ~20 MB persistents

  // RW1: phase-A weights (dead after phase B) -> ghALL
  us* vw1h = (us*)RW1;        us* vw1l = vw1h + W589;
  us* vw2h = vw1l + W589;     us* vw2l = vw2h + W589;
  us* tw1h = vw2l + W589;     us* tw1l = tw1h + W589;
  us* tw2h = tw1l + W589;     us* tw2l = tw2h + W589;
  float* ghALL = (float*)RW1;           // [1024 x GS] after weights dead
  // RW2: sequential weight reuse -> gi
  us* s2vwh = (us*)RW2;       us* s2vwl = s2vwh + W1769;
  us* s2voh = s2vwl + W1769;  us* s2vol = s2voh + W589;
  us* qawh  = (us*)RW2;       us* qawl  = qawh + W1769;
  us* qaoh  = qawl + W1769;   us* qaol  = qaoh + W589;
  us* pw2h  = (us*)RW2;       us* pw2l  = pw2h + W2359;
  float* gi = (float*)RW2;              // [1024 x GS] after pw2 dead
  // R1 timeline
  us* vidh = (us*)R1;         us* vidl = vidh + BIGe;
  us* hidh = vidl + BIGe;     us* hidl = hidh + BIGe;
  us* scrh = (us*)R1;         us* scrl = scrh + SMe;
  float* kvproj = (float*)R1;
  float* qproj  = kvproj + (size_t)4096 * 1536;
  float* kv2 = (float*)R1;
  float* qp2 = (float*)(R1 + 6291456);
  float* S2  = (float*)(R1 + 9437184);
  us* abhh = (us*)(R1 + 15728640); us* abhl = abhh + SMe;
  us* pw1h = (us*)R1;         us* pw1l = pw1h + W9437;   // spans into R2... no: R1 only (18.9MB < 28.3MB)
  us* gwihh = (us*)R1;        us* gwihl = gwihh + W1769;
  us* pjw1h = (us*)(R1 + 7077888);  us* pjw1l = pjw1h + W589;
  us* gwhhh = (us*)(R1 + 9437184);  us* gwhhl = gwhhh + W1769;
  // R2 + X: vid/attn staging, then H candidate matrix (44.4 MB spans both)
  us* vh = (us*)R2;           us* vl = vh + BIGe;
  float* attnout = (float*)R2;
  us* aoh = (us*)(R2 + 3145728); us* aol = aoh + SMe;
  float* Hbuf = (float*)R2;             // [Mtot x 768] f32 = 44,432,768 B
  // X
  float* S1 = (float*)X;
  us* cath = (us*)X;          us* catl = cath + (size_t)1024 * DPn;
  us* prehh = (us*)(X + 12582912); us* prehl = prehh + (size_t)1024 * DPn;
  // P
  us* abinh = (us*)P;         us* abinl = abinh + SMe;
  us* sch   = (us*)(P + 3145728); us* scl = sch + SMe;
  float* at_f   = (float*)(P + 6291456);
  float* vatt   = (float*)(P + 9437184);
  float* inps_f = (float*)(P + 12582912);
  us* inpsh = (us*)(P + 15728640); us* inpsl = inpsh + SMe;
  float* qf    = (float*)(P + 18874368);
  float* qhid  = (float*)(P + 18898944);
  float* gh0   = (float*)(P + 18923520);
  float* Lpart = (float*)(P + 18932736);   // 12 x 14464 f32 = 694,272 B

  // ---- phase A ----
  split4_k<<<dim3(2048, 4), 256, 0, stream>>>(v_w1, vw1h, vw1l, W589,
                                              v_w2, vw2h, vw2l, W589,
                                              t_w1, tw1h, tw1l, W589,
                                              t_w2, tw2h, tw2l, W589);
  split(video, vidh, vidl, BIGe, stream);
  mm(vidh, vidl, Dd, vw1h, vw1l, v_b1, nullptr, 0, hidh, hidl, Dd, 4096, Dd, Dd, 1, stream);
  mm(hidh, hidl, Dd, vw2h, vw2l, v_b2, nullptr, 0, vh, vl, Dd, 4096, Dd, Dd, 0, stream);
  split(script, scrh, scrl, SMe, stream);
  mm(scrh, scrl, Dd, tw1h, tw1l, t_b1, nullptr, 0, hidh, hidl, Dd, 1024, Dd, Dd, 1, stream);
  mm(hidh, hidl, Dd, tw2h, tw2l, t_b2, nullptr, 0, sch, scl, Dd, 1024, Dd, Dd, 0, stream);
  sgemm(question, t_w1, t_b1, qhid, Bn, Dd, Dd, Dd, Dd, 1, stream);
  sgemm(qhid, t_w2, t_b2, qf, Bn, Dd, Dd, Dd, Dd, 0, stream);
  split(a_texts, scrh, scrl, SMe, stream);
  mm(scrh, scrl, Dd, tw1h, tw1l, t_b1, nullptr, 0, hidh, hidl, Dd, 1024, Dd, Dd, 1, stream);
  mm(hidh, hidl, Dd, tw2h, tw2l, t_b2, at_f, Dd, nullptr, nullptr, 0, 1024, Dd, Dd, 0, stream);
  split(a_buttons, abinh, abinl, SMe, stream);

  // ---- s2v attention (K/V merged: N=1536) ----
  split4_k<<<dim3(2048, 4), 256, 0, stream>>>(s2v_win, s2vwh, s2vwl, W1769,
                                              s2v_wout, s2voh, s2vol, W589,
                                              nullptr, nullptr, nullptr, 0,
                                              nullptr, nullptr, nullptr, 0);
  mm(vh, vl, Dd, s2vwh + (size_t)Dd * Dd, s2vwl + (size_t)Dd * Dd, s2v_bin + Dd,
     kvproj, 1536, nullptr, nullptr, 0, 4096, 1536, Dd, 0, stream);
  mm(sch, scl, Dd, s2vwh, s2vwl, s2v_bin, qproj, Dd, nullptr, nullptr, 0, 1024, Dd, Dd, 0, stream);
  att_qk<<<dim3(Bn * NH, TSn / 32, TVn / 64), 256, 0, stream>>>(qproj, kvproj, S1,
                                                                TSn, TVn, 1, 1536, 0.125f);
  softmax_rows<<<Bn * NH * TSn, 256, 0, stream>>>(S1, TVn);
  att_pv<<<dim3(Bn * NH, TSn / 32), 256, 0, stream>>>(S1, kvproj + Dd, attnout,
                                                      TSn, TVn, 1, 1536);
  split(attnout, aoh, aol, SMe, stream);
  mm(aoh, aol, Dd, s2voh, s2vol, s2v_bout, vatt, Dd, nullptr, nullptr, 0, 1024, Dd, Dd, 0, stream);

  // ---- phase B: ab MLP, qa attention ----
  mm(abinh, abinl, Dd, vw1h, vw1l, v_b1, nullptr, 0, abhh, abhl, Dd, 1024, Dd, Dd, 1, stream);
  mm(abhh, abhl, Dd, vw2h, vw2l, v_b2, nullptr, 0, cath + 3 * Dd, catl + 3 * Dd, DPn,
     1024, Dd, Dd, 0, stream);
  qa_add<<<(1024 * Dd + 255) / 256, 256, 0, stream>>>(qf, at_f, cath, catl);
  split4_k<<<dim3(2048, 4), 256, 0, stream>>>(qa_win, qawh, qawl, W1769,
                                              qa_wout, qaoh, qaol, W589,
                                              nullptr, nullptr, nullptr, 0,
                                              nullptr, nullptr, nullptr, 0);
  mm(sch, scl, Dd, qawh + (size_t)Dd * Dd, qawl + (size_t)Dd * Dd, qa_bin + Dd,
     kv2, 1536, nullptr, nullptr, 0, 1024, 1536, Dd, 0, stream);
  mm(cath + 2 * Dd, catl + 2 * Dd, DPn, qawh, qawl, qa_bin, qp2, Dd, nullptr, nullptr, 0,
     1024, Dd, Dd, 0, stream);
  att_qk<<<dim3(Bn * NST * NH, 1, TSn / 64), 256, 0, stream>>>(qp2, kv2, S2,
                                                               An, TSn, NST, 1536, 0.125f);
  softmax_rows<<<Bn * NST * NH * An, 256, 0, stream>>>(S2, TSn);
  att_pv<<<dim3(Bn * NST * NH, 1), 256, 0, stream>>>(S2, kv2 + Dd, attnout,
                                                     An, TSn, NST, 1536);
  split(attnout, aoh, aol, SMe, stream);
  mm(aoh, aol, Dd, qaoh, qaol, qa_bout, nullptr, 0, cath + Dd, catl + Dd, DPn,
     1024, Dd, Dd, 0, stream);
  qv2_k<<<1024, 256, 0, stream>>>(S2, vatt, cath, catl);

  // ---- pre-MLP + GRU gates ----
  split(pre_w1, pw1h, pw1l, W9437, stream);
  mm(cath, catl, DPn, pw1h, pw1l, pre_b1, nullptr, 0, prehh, prehl, DPn,
     1024, DPn, DPn, 1, stream);
  split4_k<<<dim3(2048, 4), 256, 0, stream>>>(pre_w2, pw2h, pw2l, W2359,
                                              gru_wih, gwihh, gwihl, W1769,
                                              gru_whh, gwhhh, gwhhl, W1769,
                                              proj_w1, pjw1h, pjw1l, W589);
  mm(prehh, prehl, DPn, pw2h, pw2l, pre_b2, inps_f, Dd, inpsh, inpsl, Dd,
     1024, Dd, DPn, 0, stream);
  mm(inpsh, inpsl, Dd, gwihh, gwihl, gru_bih, gi, GSn, nullptr, nullptr, 0,
     1024, GSn, Dd, 0, stream);
  mm(inpsh, inpsl, Dd, gwhhh, gwhhl, gru_bhh, ghALL, GSn, nullptr, nullptr, 0,
     1024, GSn, Dd, 0, stream);
  sgemm(state0, gru_whh, gru_bhh, gh0, 1, GSn, Dd, Dd, GSn, 0, stream);

  // ---- candidate enumeration + logits + argmax chain ----
  combine_all<<<(Mtot * Dd + 255) / 256, 256, 0, stream>>>(gi, ghALL, gh0, inps_f,
                                                           state0, Hbuf);
  mfma_logit<<<dim3(Dd / 64, Mtot / 64), 256, 0, stream>>>(Hbuf, pjw1h, pjw1l,
                                                           proj_b1, proj_w2, Lpart);
  pick_k<<<Bn, 64, 0, stream>>>(Lpart, proj_b2, (float*)d_out);
}